// Round 1
// baseline (3748.414 us; speedup 1.0000x reference)
//
#include <hip/hip_runtime.h>
#include <hip/hip_bf16.h>
#include <cstddef>

#define N_NODES 50000
#define E_EDGES 800000
#define IN_F 512
#define HID_F 256
#define OUT_F 64
#define LN_EPS 1e-5f
#define L2_EPS 1e-12f

static __device__ __forceinline__ float clean0(float v) {
    // nan_to_num(nan=0, posinf=0, neginf=0)
    return isfinite(v) ? v : 0.0f;
}

// ---------------- degree / dinv ----------------
__global__ void deg_init_kernel(float* __restrict__ deg) {
    int i = blockIdx.x * blockDim.x + threadIdx.x;
    if (i < N_NODES) deg[i] = 1.0f;   // self loop
}

__global__ void deg_acc_kernel(const int* __restrict__ dst, float* __restrict__ deg) {
    int e = blockIdx.x * blockDim.x + threadIdx.x;
    if (e < E_EDGES) atomicAdd(&deg[dst[e]], 1.0f);
}

__global__ void deg_fin_kernel(float* __restrict__ deg) {
    int i = blockIdx.x * blockDim.x + threadIdx.x;
    if (i < N_NODES) deg[i] = rsqrtf(deg[i]);   // deg >= 1 always
}

// ---------------- row L2 norm of cleaned x ----------------
__global__ __launch_bounds__(256) void rownorm_kernel(const float* __restrict__ x,
                                                      float* __restrict__ rnorm) {
    int wid = threadIdx.x >> 6;
    int lane = threadIdx.x & 63;
    int row = blockIdx.x * 4 + wid;
    if (row >= N_NODES) return;
    const float4* xr = (const float4*)(x + (size_t)row * IN_F);
    float s = 0.0f;
    #pragma unroll
    for (int m = 0; m < 2; ++m) {
        float4 v = xr[lane * 2 + m];
        v.x = clean0(v.x); v.y = clean0(v.y); v.z = clean0(v.z); v.w = clean0(v.w);
        s += v.x * v.x + v.y * v.y + v.z * v.z + v.w * v.w;
    }
    #pragma unroll
    for (int off = 32; off > 0; off >>= 1) s += __shfl_xor(s, off, 64);
    if (lane == 0) rnorm[row] = 1.0f / fmaxf(sqrtf(s), L2_EPS);
}

// ---------------- GEMM1: h1 = xn @ W1  (by<4), skip = xn @ Wskip (by==4) ----------------
// xn = clean(x) * rnorm[row]  (row scale applied at store)
#define BM 64
#define BN 64
#define BK 16
__global__ __launch_bounds__(256) void gemm1_kernel(const float* __restrict__ x,
                                                    const float* __restrict__ rnorm,
                                                    const float* __restrict__ W1,
                                                    const float* __restrict__ Wskip,
                                                    float* __restrict__ h1,
                                                    float* __restrict__ skip) {
    __shared__ float As[BK][BM + 4];
    __shared__ float Bs[BK][BN];
    const int t = threadIdx.x;
    const int tx = t & 15;
    const int ty = t >> 4;
    const int brow = blockIdx.x * BM;
    const int by = blockIdx.y;         // 0..3 -> W1 col tiles, 4 -> Wskip

    float c[4][4] = {};

    for (int k0 = 0; k0 < IN_F; k0 += BK) {
        #pragma unroll
        for (int m = 0; m < 4; ++m) {
            int idx = m * 256 + t;
            int ra = idx >> 4;
            int ka = idx & 15;
            int grow = brow + ra;
            float v = 0.0f;
            if (grow < N_NODES) v = clean0(x[(size_t)grow * IN_F + k0 + ka]);
            As[ka][ra] = v;
        }
        #pragma unroll
        for (int m = 0; m < 4; ++m) {
            int idx = m * 256 + t;
            int kb = idx >> 6;
            int cb = idx & 63;
            float v;
            if (by < 4) v = W1[(size_t)(k0 + kb) * HID_F + by * 64 + cb];
            else        v = Wskip[(size_t)(k0 + kb) * OUT_F + cb];
            Bs[kb][cb] = v;
        }
        __syncthreads();
        #pragma unroll
        for (int k = 0; k < BK; ++k) {
            float4 av = *(const float4*)&As[k][ty * 4];
            float4 bv = *(const float4*)&Bs[k][tx * 4];
            float a[4] = {av.x, av.y, av.z, av.w};
            float b[4] = {bv.x, bv.y, bv.z, bv.w};
            #pragma unroll
            for (int i = 0; i < 4; ++i)
                #pragma unroll
                for (int j = 0; j < 4; ++j)
                    c[i][j] = fmaf(a[i], b[j], c[i][j]);
        }
        __syncthreads();
    }

    #pragma unroll
    for (int i = 0; i < 4; ++i) {
        int grow = brow + ty * 4 + i;
        if (grow >= N_NODES) break;
        float sc = rnorm[grow];
        float4 o = make_float4(c[i][0] * sc, c[i][1] * sc, c[i][2] * sc, c[i][3] * sc);
        if (by < 4) *(float4*)(h1 + (size_t)grow * HID_F + by * 64 + tx * 4) = o;
        else        *(float4*)(skip + (size_t)grow * OUT_F + tx * 4) = o;
    }
}

// ---------------- aggregation 1 (HID feats) ----------------
__global__ void agg1_init_kernel(const float* __restrict__ h1, const float* __restrict__ dinv,
                                 float* __restrict__ agg1) {
    size_t i = (size_t)blockIdx.x * blockDim.x + threadIdx.x;   // over N*HID/4
    if (i >= (size_t)N_NODES * (HID_F / 4)) return;
    int node = (int)(i >> 6);                                   // / (HID/4)
    float di = dinv[node];
    float w = di * di;
    float4 v = ((const float4*)h1)[i];
    ((float4*)agg1)[i] = make_float4(v.x * w, v.y * w, v.z * w, v.w * w);
}

__global__ __launch_bounds__(256) void agg1_edge_kernel(const int* __restrict__ src,
                                                        const int* __restrict__ dst,
                                                        const float* __restrict__ dinv,
                                                        const float* __restrict__ h1,
                                                        float* __restrict__ agg1) {
    int e = blockIdx.x * 4 + (threadIdx.x >> 6);
    if (e >= E_EDGES) return;
    int lane = threadIdx.x & 63;
    int s = src[e], d = dst[e];
    float nrm = dinv[s] * dinv[d];
    float4 v = *(const float4*)(h1 + (size_t)s * HID_F + lane * 4);
    float* o = agg1 + (size_t)d * HID_F + lane * 4;
    atomicAdd(o + 0, v.x * nrm);
    atomicAdd(o + 1, v.y * nrm);
    atomicAdd(o + 2, v.z * nrm);
    atomicAdd(o + 3, v.w * nrm);
}

// ---------------- LayerNorm(agg1 + b1) -> ReLU, one wave per node ----------------
__global__ __launch_bounds__(256) void ln_kernel(const float* __restrict__ agg1,
                                                 const float* __restrict__ b1,
                                                 const float* __restrict__ gamma,
                                                 const float* __restrict__ beta,
                                                 float* __restrict__ lnout) {
    int node = blockIdx.x * 4 + (threadIdx.x >> 6);
    if (node >= N_NODES) return;
    int lane = threadIdx.x & 63;
    float4 v = *(const float4*)(agg1 + (size_t)node * HID_F + lane * 4);
    float4 bb = *(const float4*)(b1 + lane * 4);
    v.x += bb.x; v.y += bb.y; v.z += bb.z; v.w += bb.w;
    float s = v.x + v.y + v.z + v.w;
    float s2 = v.x * v.x + v.y * v.y + v.z * v.z + v.w * v.w;
    #pragma unroll
    for (int off = 32; off > 0; off >>= 1) {
        s += __shfl_xor(s, off, 64);
        s2 += __shfl_xor(s2, off, 64);
    }
    float mu = s * (1.0f / HID_F);
    float var = s2 * (1.0f / HID_F) - mu * mu;
    float rs = rsqrtf(var + LN_EPS);
    float4 g = *(const float4*)(gamma + lane * 4);
    float4 be = *(const float4*)(beta + lane * 4);
    float4 y;
    y.x = fmaxf(0.0f, (v.x - mu) * rs * g.x + be.x);
    y.y = fmaxf(0.0f, (v.y - mu) * rs * g.y + be.y);
    y.z = fmaxf(0.0f, (v.z - mu) * rs * g.z + be.z);
    y.w = fmaxf(0.0f, (v.w - mu) * rs * g.w + be.w);
    *(float4*)(lnout + (size_t)node * HID_F + lane * 4) = y;
}

// ---------------- GEMM2: h2 = ln @ W2  (M=N, K=256, Ncols=64) ----------------
__global__ __launch_bounds__(256) void gemm2_kernel(const float* __restrict__ A,
                                                    const float* __restrict__ W2,
                                                    float* __restrict__ h2) {
    __shared__ float As[BK][BM + 4];
    __shared__ float Bs[BK][BN];
    const int t = threadIdx.x;
    const int tx = t & 15;
    const int ty = t >> 4;
    const int brow = blockIdx.x * BM;

    float c[4][4] = {};

    for (int k0 = 0; k0 < HID_F; k0 += BK) {
        #pragma unroll
        for (int m = 0; m < 4; ++m) {
            int idx = m * 256 + t;
            int ra = idx >> 4;
            int ka = idx & 15;
            int grow = brow + ra;
            As[ka][ra] = (grow < N_NODES) ? A[(size_t)grow * HID_F + k0 + ka] : 0.0f;
        }
        #pragma unroll
        for (int m = 0; m < 4; ++m) {
            int idx = m * 256 + t;
            int kb = idx >> 6;
            int cb = idx & 63;
            Bs[kb][cb] = W2[(size_t)(k0 + kb) * OUT_F + cb];
        }
        __syncthreads();
        #pragma unroll
        for (int k = 0; k < BK; ++k) {
            float4 av = *(const float4*)&As[k][ty * 4];
            float4 bv = *(const float4*)&Bs[k][tx * 4];
            float a[4] = {av.x, av.y, av.z, av.w};
            float b[4] = {bv.x, bv.y, bv.z, bv.w};
            #pragma unroll
            for (int i = 0; i < 4; ++i)
                #pragma unroll
                for (int j = 0; j < 4; ++j)
                    c[i][j] = fmaf(a[i], b[j], c[i][j]);
        }
        __syncthreads();
    }

    #pragma unroll
    for (int i = 0; i < 4; ++i) {
        int grow = brow + ty * 4 + i;
        if (grow >= N_NODES) break;
        *(float4*)(h2 + (size_t)grow * OUT_F + tx * 4) =
            make_float4(c[i][0], c[i][1], c[i][2], c[i][3]);
    }
}

// ---------------- out init: self loop + skip + b2 ----------------
__global__ void out_init_kernel(const float* __restrict__ h2, const float* __restrict__ skip,
                                const float* __restrict__ b2, const float* __restrict__ dinv,
                                float* __restrict__ out) {
    size_t i = (size_t)blockIdx.x * blockDim.x + threadIdx.x;   // over N*OUT/4
    if (i >= (size_t)N_NODES * (OUT_F / 4)) return;
    int node = (int)(i >> 4);
    int q = (int)(i & 15);
    float di = dinv[node];
    float w = di * di;
    float4 h = ((const float4*)h2)[i];
    float4 sk = ((const float4*)skip)[i];
    float4 b = ((const float4*)b2)[q];
    ((float4*)out)[i] = make_float4(h.x * w + sk.x + b.x,
                                    h.y * w + sk.y + b.y,
                                    h.z * w + sk.z + b.z,
                                    h.w * w + sk.w + b.w);
}

// ---------------- aggregation 2 (OUT feats), 16 threads per edge ----------------
__global__ void agg2_edge_kernel(const int* __restrict__ src, const int* __restrict__ dst,
                                 const float* __restrict__ dinv, const float* __restrict__ h2,
                                 float* __restrict__ out) {
    size_t t = (size_t)blockIdx.x * blockDim.x + threadIdx.x;
    int e = (int)(t >> 4);
    if (e >= E_EDGES) return;
    int q = (int)(t & 15);
    int s = src[e], d = dst[e];
    float nrm = dinv[s] * dinv[d];
    float4 v = *(const float4*)(h2 + (size_t)s * OUT_F + q * 4);
    float* o = out + (size_t)d * OUT_F + q * 4;
    atomicAdd(o + 0, v.x * nrm);
    atomicAdd(o + 1, v.y * nrm);
    atomicAdd(o + 2, v.z * nrm);
    atomicAdd(o + 3, v.w * nrm);
}

// ---------------- final nan_to_num(nan=0, posinf=20, neginf=-20) ----------------
__global__ void clean_kernel(float* __restrict__ out) {
    size_t i = (size_t)blockIdx.x * blockDim.x + threadIdx.x;
    if (i >= (size_t)N_NODES * OUT_F) return;
    float v = out[i];
    if (isnan(v)) v = 0.0f;
    else if (isinf(v)) v = (v > 0.0f) ? 20.0f : -20.0f;
    out[i] = v;
}

extern "C" void kernel_launch(void* const* d_in, const int* in_sizes, int n_in,
                              void* d_out, int out_size, void* d_ws, size_t ws_size,
                              hipStream_t stream) {
    const float* x     = (const float*)d_in[0];
    const int*   ei    = (const int*)d_in[1];
    const float* W1    = (const float*)d_in[2];
    const float* b1    = (const float*)d_in[3];
    const float* gamma = (const float*)d_in[4];
    const float* beta  = (const float*)d_in[5];
    const float* W2    = (const float*)d_in[6];
    const float* b2    = (const float*)d_in[7];
    const float* Wskip = (const float*)d_in[8];
    float* out = (float*)d_out;

    const int* src = ei;
    const int* dst = ei + E_EDGES;

    float* h1    = (float*)d_ws;                         // N*HID
    float* agg1  = h1 + (size_t)N_NODES * HID_F;         // N*HID (also holds LN output via h1 reuse)
    float* h2    = agg1 + (size_t)N_NODES * HID_F;       // N*OUT
    float* skip  = h2 + (size_t)N_NODES * OUT_F;         // N*OUT
    float* dinv  = skip + (size_t)N_NODES * OUT_F;       // N
    float* rnorm = dinv + N_NODES;                       // N

    // degree / dinv
    deg_init_kernel<<<(N_NODES + 255) / 256, 256, 0, stream>>>(dinv);
    deg_acc_kernel<<<(E_EDGES + 255) / 256, 256, 0, stream>>>(dst, dinv);
    deg_fin_kernel<<<(N_NODES + 255) / 256, 256, 0, stream>>>(dinv);

    // row norms
    rownorm_kernel<<<(N_NODES + 3) / 4, 256, 0, stream>>>(x, rnorm);

    // GEMM1 fused (h1 cols 0..255, skip cols 0..63)
    {
        dim3 g((N_NODES + BM - 1) / BM, 5);
        gemm1_kernel<<<g, 256, 0, stream>>>(x, rnorm, W1, Wskip, h1, skip);
    }

    // aggregation layer 1
    agg1_init_kernel<<<(N_NODES * (HID_F / 4) + 255) / 256, 256, 0, stream>>>(h1, dinv, agg1);
    agg1_edge_kernel<<<(E_EDGES + 3) / 4, 256, 0, stream>>>(src, dst, dinv, h1, agg1);

    // LayerNorm + ReLU (writes into h1, which is free now)
    ln_kernel<<<(N_NODES + 3) / 4, 256, 0, stream>>>(agg1, b1, gamma, beta, h1);

    // GEMM2
    gemm2_kernel<<<(N_NODES + BM - 1) / BM, 256, 0, stream>>>(h1, W2, h2);

    // out = self-loop + skip + b2, then edge aggregation, then nan_to_num
    out_init_kernel<<<(N_NODES * (OUT_F / 4) + 255) / 256, 256, 0, stream>>>(h2, skip, b2, dinv, out);
    agg2_edge_kernel<<<((size_t)E_EDGES * 16 + 255) / 256, 256, 0, stream>>>(src, dst, dinv, h2, out);
    clean_kernel<<<((size_t)N_NODES * OUT_F + 255) / 256, 256, 0, stream>>>(out);
}

// Round 2
// 687.450 us; speedup vs baseline: 5.4526x; 5.4526x over previous
//
#include <hip/hip_runtime.h>
#include <hip/hip_bf16.h>
#include <cstddef>

#define N_NODES 50000
#define E_EDGES 800000
#define IN_F 512
#define HID_F 256
#define OUT_F 64
#define LN_EPS 1e-5f
#define L2_EPS 1e-12f

static __device__ __forceinline__ float clean0(float v) {
    return isfinite(v) ? v : 0.0f;
}

// ---------------- CSR build: degree count -> scan -> scatter ----------------
__global__ void zero_deg_kernel(int* __restrict__ deg) {
    int i = blockIdx.x * blockDim.x + threadIdx.x;
    if (i < N_NODES) deg[i] = 0;
}

__global__ void count_deg_kernel(const int* __restrict__ dst, int* __restrict__ deg) {
    int e = blockIdx.x * blockDim.x + threadIdx.x;
    if (e < E_EDGES) atomicAdd(&deg[dst[e]], 1);
}

__global__ void dinv_kernel(const int* __restrict__ deg, float* __restrict__ dinv) {
    int i = blockIdx.x * blockDim.x + threadIdx.x;
    if (i < N_NODES) dinv[i] = rsqrtf((float)deg[i] + 1.0f);   // +1 self loop
}

#define SCAN_T 1024
__global__ __launch_bounds__(1024) void scan_kernel(const int* __restrict__ deg,
                                                    int* __restrict__ rowptr,
                                                    int* __restrict__ cursor) {
    __shared__ int buf[SCAN_T];
    __shared__ int carry_s;
    const int t = threadIdx.x;
    if (t == 0) carry_s = 0;
    __syncthreads();
    for (int base = 0; base < N_NODES; base += SCAN_T) {
        int v = (base + t < N_NODES) ? deg[base + t] : 0;
        buf[t] = v;
        __syncthreads();
        #pragma unroll
        for (int off = 1; off < SCAN_T; off <<= 1) {
            int y = (t >= off) ? buf[t - off] : 0;
            __syncthreads();
            buf[t] += y;
            __syncthreads();
        }
        int carry = carry_s;
        int excl = carry + buf[t] - v;
        if (base + t < N_NODES) {
            rowptr[base + t] = excl;
            cursor[base + t] = excl;
        }
        __syncthreads();
        if (t == 0) carry_s = carry + buf[SCAN_T - 1];
        __syncthreads();
    }
    if (t == 0) rowptr[N_NODES] = carry_s;
}

__global__ void scatter_kernel(const int* __restrict__ src, const int* __restrict__ dst,
                               const float* __restrict__ dinv, int* __restrict__ cursor,
                               int* __restrict__ csr_src, float* __restrict__ csr_w) {
    int e = blockIdx.x * blockDim.x + threadIdx.x;
    if (e >= E_EDGES) return;
    int s = src[e], d = dst[e];
    int pos = atomicAdd(&cursor[d], 1);
    csr_src[pos] = s;
    csr_w[pos] = dinv[s] * dinv[d];
}

// ---------------- row L2 norm of cleaned x ----------------
__global__ __launch_bounds__(256) void rownorm_kernel(const float* __restrict__ x,
                                                      float* __restrict__ rnorm) {
    int wid = threadIdx.x >> 6;
    int lane = threadIdx.x & 63;
    int row = blockIdx.x * 4 + wid;
    if (row >= N_NODES) return;
    const float4* xr = (const float4*)(x + (size_t)row * IN_F);
    float s = 0.0f;
    #pragma unroll
    for (int m = 0; m < 2; ++m) {
        float4 v = xr[lane * 2 + m];
        v.x = clean0(v.x); v.y = clean0(v.y); v.z = clean0(v.z); v.w = clean0(v.w);
        s += v.x * v.x + v.y * v.y + v.z * v.z + v.w * v.w;
    }
    #pragma unroll
    for (int off = 32; off > 0; off >>= 1) s += __shfl_xor(s, off, 64);
    if (lane == 0) rnorm[row] = 1.0f / fmaxf(sqrtf(s), L2_EPS);
}

// ---------------- GEMM1: h1 = xn @ W1 (by<4), skip = xn @ Wskip (by==4) ----------------
#define BM 64
#define BN 64
#define BK 16
__global__ __launch_bounds__(256) void gemm1_kernel(const float* __restrict__ x,
                                                    const float* __restrict__ rnorm,
                                                    const float* __restrict__ W1,
                                                    const float* __restrict__ Wskip,
                                                    float* __restrict__ h1,
                                                    float* __restrict__ skip) {
    __shared__ float As[BK][BM + 4];
    __shared__ float Bs[BK][BN];
    const int t = threadIdx.x;
    const int tx = t & 15;
    const int ty = t >> 4;
    const int brow = blockIdx.x * BM;
    const int by = blockIdx.y;

    float c[4][4] = {};

    for (int k0 = 0; k0 < IN_F; k0 += BK) {
        #pragma unroll
        for (int m = 0; m < 4; ++m) {
            int idx = m * 256 + t;
            int ra = idx >> 4;
            int ka = idx & 15;
            int grow = brow + ra;
            float v = 0.0f;
            if (grow < N_NODES) v = clean0(x[(size_t)grow * IN_F + k0 + ka]);
            As[ka][ra] = v;
        }
        #pragma unroll
        for (int m = 0; m < 4; ++m) {
            int idx = m * 256 + t;
            int kb = idx >> 6;
            int cb = idx & 63;
            float v;
            if (by < 4) v = W1[(size_t)(k0 + kb) * HID_F + by * 64 + cb];
            else        v = Wskip[(size_t)(k0 + kb) * OUT_F + cb];
            Bs[kb][cb] = v;
        }
        __syncthreads();
        #pragma unroll
        for (int k = 0; k < BK; ++k) {
            float4 av = *(const float4*)&As[k][ty * 4];
            float4 bv = *(const float4*)&Bs[k][tx * 4];
            float a[4] = {av.x, av.y, av.z, av.w};
            float b[4] = {bv.x, bv.y, bv.z, bv.w};
            #pragma unroll
            for (int i = 0; i < 4; ++i)
                #pragma unroll
                for (int j = 0; j < 4; ++j)
                    c[i][j] = fmaf(a[i], b[j], c[i][j]);
        }
        __syncthreads();
    }

    #pragma unroll
    for (int i = 0; i < 4; ++i) {
        int grow = brow + ty * 4 + i;
        if (grow >= N_NODES) break;
        float sc = rnorm[grow];
        float4 o = make_float4(c[i][0] * sc, c[i][1] * sc, c[i][2] * sc, c[i][3] * sc);
        if (by < 4) *(float4*)(h1 + (size_t)grow * HID_F + by * 64 + tx * 4) = o;
        else        *(float4*)(skip + (size_t)grow * OUT_F + tx * 4) = o;
    }
}

// ---------------- aggregation 1: CSR gather, one wave per node (256 feats) ----------------
__global__ __launch_bounds__(256) void agg1_gather_kernel(const float* __restrict__ h1,
                                                          const float* __restrict__ dinv,
                                                          const int* __restrict__ rowptr,
                                                          const int* __restrict__ csr_src,
                                                          const float* __restrict__ csr_w,
                                                          float* __restrict__ agg1) {
    int node = blockIdx.x * 4 + (threadIdx.x >> 6);
    if (node >= N_NODES) return;
    int lane = threadIdx.x & 63;
    const float4* hp = (const float4*)h1;
    float di = dinv[node];
    float ws = di * di;                       // self loop weight
    float4 sv = hp[(size_t)node * 64 + lane];
    float4 acc = make_float4(sv.x * ws, sv.y * ws, sv.z * ws, sv.w * ws);
    int jb = rowptr[node], je = rowptr[node + 1];
    int j = jb;
    for (; j + 1 < je; j += 2) {
        int s0 = csr_src[j];
        int s1 = csr_src[j + 1];
        float w0 = csr_w[j];
        float w1 = csr_w[j + 1];
        float4 v0 = hp[(size_t)s0 * 64 + lane];
        float4 v1 = hp[(size_t)s1 * 64 + lane];
        acc.x = fmaf(v0.x, w0, acc.x); acc.y = fmaf(v0.y, w0, acc.y);
        acc.z = fmaf(v0.z, w0, acc.z); acc.w = fmaf(v0.w, w0, acc.w);
        acc.x = fmaf(v1.x, w1, acc.x); acc.y = fmaf(v1.y, w1, acc.y);
        acc.z = fmaf(v1.z, w1, acc.z); acc.w = fmaf(v1.w, w1, acc.w);
    }
    if (j < je) {
        int s0 = csr_src[j];
        float w0 = csr_w[j];
        float4 v0 = hp[(size_t)s0 * 64 + lane];
        acc.x = fmaf(v0.x, w0, acc.x); acc.y = fmaf(v0.y, w0, acc.y);
        acc.z = fmaf(v0.z, w0, acc.z); acc.w = fmaf(v0.w, w0, acc.w);
    }
    ((float4*)agg1)[(size_t)node * 64 + lane] = acc;
}

// ---------------- LayerNorm(agg1 + b1) -> ReLU ----------------
__global__ __launch_bounds__(256) void ln_kernel(const float* __restrict__ agg1,
                                                 const float* __restrict__ b1,
                                                 const float* __restrict__ gamma,
                                                 const float* __restrict__ beta,
                                                 float* __restrict__ lnout) {
    int node = blockIdx.x * 4 + (threadIdx.x >> 6);
    if (node >= N_NODES) return;
    int lane = threadIdx.x & 63;
    float4 v = *(const float4*)(agg1 + (size_t)node * HID_F + lane * 4);
    float4 bb = *(const float4*)(b1 + lane * 4);
    v.x += bb.x; v.y += bb.y; v.z += bb.z; v.w += bb.w;
    float s = v.x + v.y + v.z + v.w;
    float s2 = v.x * v.x + v.y * v.y + v.z * v.z + v.w * v.w;
    #pragma unroll
    for (int off = 32; off > 0; off >>= 1) {
        s += __shfl_xor(s, off, 64);
        s2 += __shfl_xor(s2, off, 64);
    }
    float mu = s * (1.0f / HID_F);
    float var = s2 * (1.0f / HID_F) - mu * mu;
    float rs = rsqrtf(var + LN_EPS);
    float4 g = *(const float4*)(gamma + lane * 4);
    float4 be = *(const float4*)(beta + lane * 4);
    float4 y;
    y.x = fmaxf(0.0f, (v.x - mu) * rs * g.x + be.x);
    y.y = fmaxf(0.0f, (v.y - mu) * rs * g.y + be.y);
    y.z = fmaxf(0.0f, (v.z - mu) * rs * g.z + be.z);
    y.w = fmaxf(0.0f, (v.w - mu) * rs * g.w + be.w);
    *(float4*)(lnout + (size_t)node * HID_F + lane * 4) = y;
}

// ---------------- GEMM2: h2 = ln @ W2 ----------------
__global__ __launch_bounds__(256) void gemm2_kernel(const float* __restrict__ A,
                                                    const float* __restrict__ W2,
                                                    float* __restrict__ h2) {
    __shared__ float As[BK][BM + 4];
    __shared__ float Bs[BK][BN];
    const int t = threadIdx.x;
    const int tx = t & 15;
    const int ty = t >> 4;
    const int brow = blockIdx.x * BM;

    float c[4][4] = {};

    for (int k0 = 0; k0 < HID_F; k0 += BK) {
        #pragma unroll
        for (int m = 0; m < 4; ++m) {
            int idx = m * 256 + t;
            int ra = idx >> 4;
            int ka = idx & 15;
            int grow = brow + ra;
            As[ka][ra] = (grow < N_NODES) ? A[(size_t)grow * HID_F + k0 + ka] : 0.0f;
        }
        #pragma unroll
        for (int m = 0; m < 4; ++m) {
            int idx = m * 256 + t;
            int kb = idx >> 6;
            int cb = idx & 63;
            Bs[kb][cb] = W2[(size_t)(k0 + kb) * OUT_F + cb];
        }
        __syncthreads();
        #pragma unroll
        for (int k = 0; k < BK; ++k) {
            float4 av = *(const float4*)&As[k][ty * 4];
            float4 bv = *(const float4*)&Bs[k][tx * 4];
            float a[4] = {av.x, av.y, av.z, av.w};
            float b[4] = {bv.x, bv.y, bv.z, bv.w};
            #pragma unroll
            for (int i = 0; i < 4; ++i)
                #pragma unroll
                for (int j = 0; j < 4; ++j)
                    c[i][j] = fmaf(a[i], b[j], c[i][j]);
        }
        __syncthreads();
    }

    #pragma unroll
    for (int i = 0; i < 4; ++i) {
        int grow = brow + ty * 4 + i;
        if (grow >= N_NODES) break;
        *(float4*)(h2 + (size_t)grow * OUT_F + tx * 4) =
            make_float4(c[i][0], c[i][1], c[i][2], c[i][3]);
    }
}

// ---------------- aggregation 2: CSR gather + skip + b2 + nan_to_num -> out ----------------
__global__ __launch_bounds__(256) void agg2_gather_kernel(const float* __restrict__ h2,
                                                          const float* __restrict__ skip,
                                                          const float* __restrict__ b2,
                                                          const float* __restrict__ dinv,
                                                          const int* __restrict__ rowptr,
                                                          const int* __restrict__ csr_src,
                                                          const float* __restrict__ csr_w,
                                                          float* __restrict__ out) {
    int node = blockIdx.x * 4 + (threadIdx.x >> 6);
    if (node >= N_NODES) return;
    int lane = threadIdx.x & 63;
    float di = dinv[node];
    float acc = h2[(size_t)node * OUT_F + lane] * di * di;
    int jb = rowptr[node], je = rowptr[node + 1];
    int j = jb;
    for (; j + 1 < je; j += 2) {
        int s0 = csr_src[j];
        int s1 = csr_src[j + 1];
        float w0 = csr_w[j];
        float w1 = csr_w[j + 1];
        float v0 = h2[(size_t)s0 * OUT_F + lane];
        float v1 = h2[(size_t)s1 * OUT_F + lane];
        acc = fmaf(v0, w0, acc);
        acc = fmaf(v1, w1, acc);
    }
    if (j < je) {
        acc = fmaf(h2[(size_t)csr_src[j] * OUT_F + lane], csr_w[j], acc);
    }
    float v = acc + skip[(size_t)node * OUT_F + lane] + b2[lane];
    if (isnan(v)) v = 0.0f;
    else if (isinf(v)) v = (v > 0.0f) ? 20.0f : -20.0f;
    out[(size_t)node * OUT_F + lane] = v;
}

extern "C" void kernel_launch(void* const* d_in, const int* in_sizes, int n_in,
                              void* d_out, int out_size, void* d_ws, size_t ws_size,
                              hipStream_t stream) {
    const float* x     = (const float*)d_in[0];
    const int*   ei    = (const int*)d_in[1];
    const float* W1    = (const float*)d_in[2];
    const float* b1    = (const float*)d_in[3];
    const float* gamma = (const float*)d_in[4];
    const float* beta  = (const float*)d_in[5];
    const float* W2    = (const float*)d_in[6];
    const float* b2    = (const float*)d_in[7];
    const float* Wskip = (const float*)d_in[8];
    float* out = (float*)d_out;

    const int* src = ei;
    const int* dst = ei + E_EDGES;

    float* h1    = (float*)d_ws;                          // N*HID
    float* agg1  = h1 + (size_t)N_NODES * HID_F;          // N*HID
    float* h2    = agg1 + (size_t)N_NODES * HID_F;        // N*OUT
    float* skip  = h2 + (size_t)N_NODES * OUT_F;          // N*OUT
    float* dinv  = skip + (size_t)N_NODES * OUT_F;        // N
    float* rnorm = dinv + N_NODES;                        // N
    float* csr_w = rnorm + N_NODES;                       // E
    int* deg     = (int*)(csr_w + E_EDGES);               // N
    int* rowptr  = deg + N_NODES;                         // N+1
    int* cursor  = rowptr + N_NODES + 1;                  // N
    int* csr_src = cursor + N_NODES;                      // E

    // ---- CSR build + dinv ----
    zero_deg_kernel<<<(N_NODES + 255) / 256, 256, 0, stream>>>(deg);
    count_deg_kernel<<<(E_EDGES + 255) / 256, 256, 0, stream>>>(dst, deg);
    dinv_kernel<<<(N_NODES + 255) / 256, 256, 0, stream>>>(deg, dinv);
    scan_kernel<<<1, SCAN_T, 0, stream>>>(deg, rowptr, cursor);
    scatter_kernel<<<(E_EDGES + 255) / 256, 256, 0, stream>>>(src, dst, dinv, cursor,
                                                              csr_src, csr_w);

    // ---- row norms ----
    rownorm_kernel<<<(N_NODES + 3) / 4, 256, 0, stream>>>(x, rnorm);

    // ---- GEMM1 fused (h1 + skip) ----
    {
        dim3 g((N_NODES + BM - 1) / BM, 5);
        gemm1_kernel<<<g, 256, 0, stream>>>(x, rnorm, W1, Wskip, h1, skip);
    }

    // ---- aggregation 1 (CSR gather) ----
    agg1_gather_kernel<<<(N_NODES + 3) / 4, 256, 0, stream>>>(h1, dinv, rowptr,
                                                              csr_src, csr_w, agg1);

    // ---- LayerNorm + ReLU (into h1, free now) ----
    ln_kernel<<<(N_NODES + 3) / 4, 256, 0, stream>>>(agg1, b1, gamma, beta, h1);

    // ---- GEMM2 ----
    gemm2_kernel<<<(N_NODES + BM - 1) / BM, 256, 0, stream>>>(h1, W2, h2);

    // ---- aggregation 2 (CSR gather, fused epilogue) ----
    agg2_gather_kernel<<<(N_NODES + 3) / 4, 256, 0, stream>>>(h2, skip, b2, dinv, rowptr,
                                                              csr_src, csr_w, out);
}

// Round 3
// 578.617 us; speedup vs baseline: 6.4782x; 1.1881x over previous
//
#include <hip/hip_runtime.h>
#include <hip/hip_bf16.h>
#include <cstddef>

#define N_NODES 50000
#define E_EDGES 800000
#define IN_F 512
#define HID_F 256
#define OUT_F 64
#define NCAT 320              // HID + OUT combined GEMM1 output cols
#define LN_EPS 1e-5f
#define L2_EPS 1e-12f

typedef unsigned short ushortT;
typedef __attribute__((ext_vector_type(8))) short short8;
typedef __attribute__((ext_vector_type(4))) float f32x4;

static __device__ __forceinline__ float clean0(float v) {
    return isfinite(v) ? v : 0.0f;
}

static __device__ __forceinline__ ushortT f2bf(float f) {
    __hip_bfloat16 h = __float2bfloat16(f);
    return *reinterpret_cast<ushortT*>(&h);
}

// ---------------- CSR build ----------------
__global__ void zero_deg_kernel(int* __restrict__ deg) {
    int i = blockIdx.x * blockDim.x + threadIdx.x;
    if (i < N_NODES) deg[i] = 0;
}

__global__ void count_deg_kernel(const int* __restrict__ dst, int* __restrict__ deg) {
    int e = blockIdx.x * blockDim.x + threadIdx.x;
    if (e < E_EDGES) atomicAdd(&deg[dst[e]], 1);
}

__global__ void dinv_kernel(const int* __restrict__ deg, float* __restrict__ dinv) {
    int i = blockIdx.x * blockDim.x + threadIdx.x;
    if (i < N_NODES) dinv[i] = rsqrtf((float)deg[i] + 1.0f);   // +1 self loop
}

// single-block scan: thread-serial chunk + one 10-step block scan
#define SCAN_T 1024
#define SCAN_CHUNK 49          // ceil(50000/1024)
__global__ __launch_bounds__(1024) void scan_kernel(const int* __restrict__ deg,
                                                    int* __restrict__ rowptr,
                                                    int* __restrict__ cursor) {
    __shared__ int sums[SCAN_T];
    const int t = threadIdx.x;
    const int base = t * SCAN_CHUNK;
    int local[SCAN_CHUNK];
    int s = 0;
    #pragma unroll
    for (int i = 0; i < SCAN_CHUNK; ++i) {
        int idx = base + i;
        int v = (idx < N_NODES) ? deg[idx] : 0;
        local[i] = s;                       // exclusive within chunk
        s += v;
    }
    sums[t] = s;
    __syncthreads();
    int x = s;
    for (int off = 1; off < SCAN_T; off <<= 1) {
        int y = (t >= off) ? sums[t - off] : 0;
        __syncthreads();
        x += y;
        sums[t] = x;
        __syncthreads();
    }
    int excl = x - s;                       // exclusive block prefix
    #pragma unroll
    for (int i = 0; i < SCAN_CHUNK; ++i) {
        int idx = base + i;
        if (idx < N_NODES) {
            int p = excl + local[i];
            rowptr[idx] = p;
            cursor[idx] = p;
        }
    }
    if (t == SCAN_T - 1) rowptr[N_NODES] = x;
}

__global__ void scatter_kernel(const int* __restrict__ src, const int* __restrict__ dst,
                               const float* __restrict__ dinv, int* __restrict__ cursor,
                               int* __restrict__ csr_src, float* __restrict__ csr_w) {
    int e = blockIdx.x * blockDim.x + threadIdx.x;
    if (e >= E_EDGES) return;
    int s = src[e], d = dst[e];
    int pos = atomicAdd(&cursor[d], 1);
    csr_src[pos] = s;
    csr_w[pos] = dinv[s] * dinv[d];
}

// ---------------- weight convert: WcatT[n][k] = bf16(W1 | Wskip), n-major ----------------
__global__ void wcvt_kernel(const float* __restrict__ W1, const float* __restrict__ Wskip,
                            ushortT* __restrict__ WcatT) {
    int id = blockIdx.x * blockDim.x + threadIdx.x;
    if (id >= NCAT * IN_F) return;
    int n = id >> 9;            // /512
    int k = id & 511;
    float v = (n < HID_F) ? W1[(size_t)k * HID_F + n]
                          : Wskip[(size_t)k * OUT_F + (n - HID_F)];
    WcatT[id] = f2bf(v);
}

// ---------------- rownorm: xb[row][:] = bf16(clean(x) / max(||x||, eps)) ----------------
__global__ __launch_bounds__(256) void rownorm_kernel(const float* __restrict__ x,
                                                      ushortT* __restrict__ xb) {
    int row = blockIdx.x * 4 + (threadIdx.x >> 6);
    if (row >= N_NODES) return;
    int lane = threadIdx.x & 63;
    const float4* xr = (const float4*)(x + (size_t)row * IN_F);
    float4 v0 = xr[lane * 2];
    float4 v1 = xr[lane * 2 + 1];
    v0.x = clean0(v0.x); v0.y = clean0(v0.y); v0.z = clean0(v0.z); v0.w = clean0(v0.w);
    v1.x = clean0(v1.x); v1.y = clean0(v1.y); v1.z = clean0(v1.z); v1.w = clean0(v1.w);
    float s = v0.x*v0.x + v0.y*v0.y + v0.z*v0.z + v0.w*v0.w
            + v1.x*v1.x + v1.y*v1.y + v1.z*v1.z + v1.w*v1.w;
    #pragma unroll
    for (int off = 32; off > 0; off >>= 1) s += __shfl_xor(s, off, 64);
    float rn = 1.0f / fmaxf(sqrtf(s), L2_EPS);
    ushortT o[8];
    o[0] = f2bf(v0.x * rn); o[1] = f2bf(v0.y * rn); o[2] = f2bf(v0.z * rn); o[3] = f2bf(v0.w * rn);
    o[4] = f2bf(v1.x * rn); o[5] = f2bf(v1.y * rn); o[6] = f2bf(v1.z * rn); o[7] = f2bf(v1.w * rn);
    *(uint4*)(xb + (size_t)row * IN_F + lane * 8) = *(uint4*)o;
}

// ---------------- GEMM1 (MFMA bf16): [N x 512] @ [512 x 320] -> h1 fp32 | skip fp32 ----------------
#define G1_BM 128
#define G1_BK 64
#define A_PITCH 72            // bf16 elems per LDS row (144 B, conflict-free)
__global__ __launch_bounds__(256) void gemm1_mfma_kernel(const ushortT* __restrict__ xb,
                                                         const ushortT* __restrict__ WcatT,
                                                         float* __restrict__ h1,
                                                         float* __restrict__ skip) {
    __shared__ ushortT As[G1_BM * A_PITCH];
    __shared__ ushortT Bs[64 * A_PITCH];
    const int t = threadIdx.x;
    const int brow = blockIdx.x * G1_BM;
    const int bn = blockIdx.y;             // 0..3 -> h1 col tile, 4 -> skip
    const int lane = t & 63;
    const int wid = t >> 6;
    const int wr = wid >> 1, wc = wid & 1; // 2x2 waves, wave tile 64x32
    const int lr = lane & 15, lk = lane >> 4;
    const int ar = t >> 3, asl = t & 7;    // staging: row, 16B-slot

    f32x4 acc[4][2] = {};
    uint4 areg[4];
    uint4 breg[2];

    // prefetch k0 = 0
    #pragma unroll
    for (int i = 0; i < 4; ++i) {
        int r = brow + ar + 32 * i;
        r = (r < N_NODES) ? r : (N_NODES - 1);
        areg[i] = *(const uint4*)(xb + (size_t)r * IN_F + asl * 8);
    }
    #pragma unroll
    for (int i = 0; i < 2; ++i) {
        int r = bn * 64 + ar + 32 * i;
        breg[i] = *(const uint4*)(WcatT + (size_t)r * IN_F + asl * 8);
    }

    for (int k0 = 0; k0 < IN_F; k0 += G1_BK) {
        __syncthreads();
        #pragma unroll
        for (int i = 0; i < 4; ++i)
            *(uint4*)&As[(ar + 32 * i) * A_PITCH + asl * 8] = areg[i];
        #pragma unroll
        for (int i = 0; i < 2; ++i)
            *(uint4*)&Bs[(ar + 32 * i) * A_PITCH + asl * 8] = breg[i];
        __syncthreads();
        if (k0 + G1_BK < IN_F) {
            int kn = k0 + G1_BK;
            #pragma unroll
            for (int i = 0; i < 4; ++i) {
                int r = brow + ar + 32 * i;
                r = (r < N_NODES) ? r : (N_NODES - 1);
                areg[i] = *(const uint4*)(xb + (size_t)r * IN_F + kn + asl * 8);
            }
            #pragma unroll
            for (int i = 0; i < 2; ++i) {
                int r = bn * 64 + ar + 32 * i;
                breg[i] = *(const uint4*)(WcatT + (size_t)r * IN_F + kn + asl * 8);
            }
        }
        #pragma unroll
        for (int kk = 0; kk < 2; ++kk) {
            short8 a[4], b[2];
            #pragma unroll
            for (int m = 0; m < 4; ++m)
                a[m] = *(const short8*)&As[(wr * 64 + m * 16 + lr) * A_PITCH + kk * 32 + lk * 8];
            #pragma unroll
            for (int n = 0; n < 2; ++n)
                b[n] = *(const short8*)&Bs[(wc * 32 + n * 16 + lr) * A_PITCH + kk * 32 + lk * 8];
            #pragma unroll
            for (int m = 0; m < 4; ++m)
                #pragma unroll
                for (int n = 0; n < 2; ++n)
                    acc[m][n] = __builtin_amdgcn_mfma_f32_16x16x32_bf16(a[m], b[n], acc[m][n], 0, 0, 0);
        }
    }

    // epilogue: D row = wr*64 + m*16 + lk*4 + v ; col = wc*32 + n*16 + lr
    if (bn < 4) {
        #pragma unroll
        for (int m = 0; m < 4; ++m) {
            int grow = brow + wr * 64 + m * 16 + lk * 4;
            #pragma unroll
            for (int v = 0; v < 4; ++v) {
                if (grow + v < N_NODES) {
                    float* rowp = h1 + (size_t)(grow + v) * HID_F + bn * 64 + wc * 32 + lr;
                    rowp[0]  = acc[m][0][v];
                    rowp[16] = acc[m][1][v];
                }
            }
        }
    } else {
        #pragma unroll
        for (int m = 0; m < 4; ++m) {
            int grow = brow + wr * 64 + m * 16 + lk * 4;
            #pragma unroll
            for (int v = 0; v < 4; ++v) {
                if (grow + v < N_NODES) {
                    float* rowp = skip + (size_t)(grow + v) * OUT_F + wc * 32 + lr;
                    rowp[0]  = acc[m][0][v];
                    rowp[16] = acc[m][1][v];
                }
            }
        }
    }
}

// ---------------- aggregation 1: CSR gather (fp32 h1) ----------------
__global__ __launch_bounds__(256) void agg1_gather_kernel(const float* __restrict__ h1,
                                                          const float* __restrict__ dinv,
                                                          const int* __restrict__ rowptr,
                                                          const int* __restrict__ csr_src,
                                                          const float* __restrict__ csr_w,
                                                          float* __restrict__ agg1) {
    int node = blockIdx.x * 4 + (threadIdx.x >> 6);
    if (node >= N_NODES) return;
    int lane = threadIdx.x & 63;
    const float4* hp = (const float4*)h1;
    float di = dinv[node];
    float ws = di * di;
    float4 sv = hp[(size_t)node * 64 + lane];
    float4 acc = make_float4(sv.x * ws, sv.y * ws, sv.z * ws, sv.w * ws);
    int jb = rowptr[node], je = rowptr[node + 1];
    int j = jb;
    for (; j + 1 < je; j += 2) {
        int s0 = csr_src[j];
        int s1 = csr_src[j + 1];
        float w0 = csr_w[j];
        float w1 = csr_w[j + 1];
        float4 v0 = hp[(size_t)s0 * 64 + lane];
        float4 v1 = hp[(size_t)s1 * 64 + lane];
        acc.x = fmaf(v0.x, w0, acc.x); acc.y = fmaf(v0.y, w0, acc.y);
        acc.z = fmaf(v0.z, w0, acc.z); acc.w = fmaf(v0.w, w0, acc.w);
        acc.x = fmaf(v1.x, w1, acc.x); acc.y = fmaf(v1.y, w1, acc.y);
        acc.z = fmaf(v1.z, w1, acc.z); acc.w = fmaf(v1.w, w1, acc.w);
    }
    if (j < je) {
        int s0 = csr_src[j];
        float w0 = csr_w[j];
        float4 v0 = hp[(size_t)s0 * 64 + lane];
        acc.x = fmaf(v0.x, w0, acc.x); acc.y = fmaf(v0.y, w0, acc.y);
        acc.z = fmaf(v0.z, w0, acc.z); acc.w = fmaf(v0.w, w0, acc.w);
    }
    ((float4*)agg1)[(size_t)node * 64 + lane] = acc;
}

// ---------------- LayerNorm(agg1 + b1) -> ReLU (fp32 out) ----------------
__global__ __launch_bounds__(256) void ln_kernel(const float* __restrict__ agg1,
                                                 const float* __restrict__ b1,
                                                 const float* __restrict__ gamma,
                                                 const float* __restrict__ beta,
                                                 float* __restrict__ lnout) {
    int node = blockIdx.x * 4 + (threadIdx.x >> 6);
    if (node >= N_NODES) return;
    int lane = threadIdx.x & 63;
    float4 v = *(const float4*)(agg1 + (size_t)node * HID_F + lane * 4);
    float4 bb = *(const float4*)(b1 + lane * 4);
    v.x += bb.x; v.y += bb.y; v.z += bb.z; v.w += bb.w;
    float s = v.x + v.y + v.z + v.w;
    float s2 = v.x * v.x + v.y * v.y + v.z * v.z + v.w * v.w;
    #pragma unroll
    for (int off = 32; off > 0; off >>= 1) {
        s += __shfl_xor(s, off, 64);
        s2 += __shfl_xor(s2, off, 64);
    }
    float mu = s * (1.0f / HID_F);
    float var = s2 * (1.0f / HID_F) - mu * mu;
    float rs = rsqrtf(var + LN_EPS);
    float4 g = *(const float4*)(gamma + lane * 4);
    float4 be = *(const float4*)(beta + lane * 4);
    float4 y;
    y.x = fmaxf(0.0f, (v.x - mu) * rs * g.x + be.x);
    y.y = fmaxf(0.0f, (v.y - mu) * rs * g.y + be.y);
    y.z = fmaxf(0.0f, (v.z - mu) * rs * g.z + be.z);
    y.w = fmaxf(0.0f, (v.w - mu) * rs * g.w + be.w);
    *(float4*)(lnout + (size_t)node * HID_F + lane * 4) = y;
}

// ---------------- GEMM2 (fp32 vector): h2 = ln @ W2 ----------------
#define BM 64
#define BN 64
#define BK 16
__global__ __launch_bounds__(256) void gemm2_kernel(const float* __restrict__ A,
                                                    const float* __restrict__ W2,
                                                    float* __restrict__ h2) {
    __shared__ float As[BK][BM + 4];
    __shared__ float Bs[BK][BN];
    const int t = threadIdx.x;
    const int tx = t & 15;
    const int ty = t >> 4;
    const int brow = blockIdx.x * BM;

    float c[4][4] = {};

    for (int k0 = 0; k0 < HID_F; k0 += BK) {
        #pragma unroll
        for (int m = 0; m < 4; ++m) {
            int idx = m * 256 + t;
            int ra = idx >> 4;
            int ka = idx & 15;
            int grow = brow + ra;
            As[ka][ra] = (grow < N_NODES) ? A[(size_t)grow * HID_F + k0 + ka] : 0.0f;
        }
        #pragma unroll
        for (int m = 0; m < 4; ++m) {
            int idx = m * 256 + t;
            int kb = idx >> 6;
            int cb = idx & 63;
            Bs[kb][cb] = W2[(size_t)(k0 + kb) * OUT_F + cb];
        }
        __syncthreads();
        #pragma unroll
        for (int k = 0; k < BK; ++k) {
            float4 av = *(const float4*)&As[k][ty * 4];
            float4 bv = *(const float4*)&Bs[k][tx * 4];
            float a[4] = {av.x, av.y, av.z, av.w};
            float b[4] = {bv.x, bv.y, bv.z, bv.w};
            #pragma unroll
            for (int i = 0; i < 4; ++i)
                #pragma unroll
                for (int j = 0; j < 4; ++j)
                    c[i][j] = fmaf(a[i], b[j], c[i][j]);
        }
        __syncthreads();
    }

    #pragma unroll
    for (int i = 0; i < 4; ++i) {
        int grow = brow + ty * 4 + i;
        if (grow >= N_NODES) break;
        *(float4*)(h2 + (size_t)grow * OUT_F + tx * 4) =
            make_float4(c[i][0], c[i][1], c[i][2], c[i][3]);
    }
}

// ---------------- aggregation 2: CSR gather + skip + b2 + nan_to_num -> out ----------------
__global__ __launch_bounds__(256) void agg2_gather_kernel(const float* __restrict__ h2,
                                                          const float* __restrict__ skip,
                                                          const float* __restrict__ b2,
                                                          const float* __restrict__ dinv,
                                                          const int* __restrict__ rowptr,
                                                          const int* __restrict__ csr_src,
                                                          const float* __restrict__ csr_w,
                                                          float* __restrict__ out) {
    int node = blockIdx.x * 4 + (threadIdx.x >> 6);
    if (node >= N_NODES) return;
    int lane = threadIdx.x & 63;
    float di = dinv[node];
    float acc = h2[(size_t)node * OUT_F + lane] * di * di;
    int jb = rowptr[node], je = rowptr[node + 1];
    int j = jb;
    for (; j + 1 < je; j += 2) {
        int s0 = csr_src[j];
        int s1 = csr_src[j + 1];
        float w0 = csr_w[j];
        float w1 = csr_w[j + 1];
        float v0 = h2[(size_t)s0 * OUT_F + lane];
        float v1 = h2[(size_t)s1 * OUT_F + lane];
        acc = fmaf(v0, w0, acc);
        acc = fmaf(v1, w1, acc);
    }
    if (j < je) {
        acc = fmaf(h2[(size_t)csr_src[j] * OUT_F + lane], csr_w[j], acc);
    }
    float v = acc + skip[(size_t)node * OUT_F + lane] + b2[lane];
    if (isnan(v)) v = 0.0f;
    else if (isinf(v)) v = (v > 0.0f) ? 20.0f : -20.0f;
    out[(size_t)node * OUT_F + lane] = v;
}

extern "C" void kernel_launch(void* const* d_in, const int* in_sizes, int n_in,
                              void* d_out, int out_size, void* d_ws, size_t ws_size,
                              hipStream_t stream) {
    const float* x     = (const float*)d_in[0];
    const int*   ei    = (const int*)d_in[1];
    const float* W1    = (const float*)d_in[2];
    const float* b1    = (const float*)d_in[3];
    const float* gamma = (const float*)d_in[4];
    const float* beta  = (const float*)d_in[5];
    const float* W2    = (const float*)d_in[6];
    const float* b2    = (const float*)d_in[7];
    const float* Wskip = (const float*)d_in[8];
    float* out = (float*)d_out;

    const int* src = ei;
    const int* dst = ei + E_EDGES;

    // ws layout (region0 shared by xb then agg1: both N*1024 bytes)
    float* region0 = (float*)d_ws;                        // N*HID floats == N*IN bf16
    ushortT* xb    = (ushortT*)region0;
    float* agg1    = region0;
    float* h1      = region0 + (size_t)N_NODES * HID_F;   // N*HID
    float* h2      = h1 + (size_t)N_NODES * HID_F;        // N*OUT
    float* skip    = h2 + (size_t)N_NODES * OUT_F;        // N*OUT
    float* dinv    = skip + (size_t)N_NODES * OUT_F;      // N
    float* csr_w   = dinv + N_NODES;                      // E
    ushortT* WcatT = (ushortT*)(csr_w + E_EDGES);         // 320*512 bf16
    int* deg       = (int*)(WcatT + (size_t)NCAT * IN_F); // N
    int* rowptr    = deg + N_NODES;                       // N+1
    int* cursor    = rowptr + N_NODES + 1;                // N
    int* csr_src   = cursor + N_NODES;                    // E

    // ---- CSR build + dinv ----
    zero_deg_kernel<<<(N_NODES + 255) / 256, 256, 0, stream>>>(deg);
    count_deg_kernel<<<(E_EDGES + 255) / 256, 256, 0, stream>>>(dst, deg);
    dinv_kernel<<<(N_NODES + 255) / 256, 256, 0, stream>>>(deg, dinv);
    scan_kernel<<<1, SCAN_T, 0, stream>>>(deg, rowptr, cursor);
    scatter_kernel<<<(E_EDGES + 255) / 256, 256, 0, stream>>>(src, dst, dinv, cursor,
                                                              csr_src, csr_w);

    // ---- weight convert + row norm (bf16) ----
    wcvt_kernel<<<(NCAT * IN_F + 255) / 256, 256, 0, stream>>>(W1, Wskip, WcatT);
    rownorm_kernel<<<(N_NODES + 3) / 4, 256, 0, stream>>>(x, xb);

    // ---- GEMM1 MFMA (h1 + skip) ----
    {
        dim3 g((N_NODES + G1_BM - 1) / G1_BM, 5);
        gemm1_mfma_kernel<<<g, 256, 0, stream>>>(xb, WcatT, h1, skip);
    }

    // ---- aggregation 1 (CSR gather) -> agg1 (overwrites xb region; xb dead) ----
    agg1_gather_kernel<<<(N_NODES + 3) / 4, 256, 0, stream>>>(h1, dinv, rowptr,
                                                              csr_src, csr_w, agg1);

    // ---- LayerNorm + ReLU (into h1) ----
    ln_kernel<<<(N_NODES + 3) / 4, 256, 0, stream>>>(agg1, b1, gamma, beta, h1);

    // ---- GEMM2 (fp32) ----
    gemm2_kernel<<<(N_NODES + BM - 1) / BM, 256, 0, stream>>>(h1, W2, h2);

    // ---- aggregation 2 (CSR gather, fused epilogue) ----
    agg2_gather_kernel<<<(N_NODES + 3) / 4, 256, 0, stream>>>(h2, skip, b2, dinv, rowptr,
                                                              csr_src, csr_w, out);
}

// Round 4
// 429.117 us; speedup vs baseline: 8.7352x; 1.3484x over previous
//
#include <hip/hip_runtime.h>
#include <hip/hip_bf16.h>
#include <cstddef>

#define N_NODES 50000
#define E_EDGES 800000
#define IN_F 512
#define HID_F 256
#define OUT_F 64
#define NCAT 320              // HID + OUT combined GEMM1 output cols
#define LN_EPS 1e-5f
#define L2_EPS 1e-12f

typedef unsigned short ushortT;
typedef __attribute__((ext_vector_type(8))) short short8;
typedef __attribute__((ext_vector_type(4))) float f32x4;

static __device__ __forceinline__ float clean0(float v) {
    return isfinite(v) ? v : 0.0f;
}

static __device__ __forceinline__ ushortT f2bf(float f) {
    __hip_bfloat16 h = __float2bfloat16(f);
    return *reinterpret_cast<ushortT*>(&h);
}

static __device__ __forceinline__ void bf4_to_f32(uint2 u, float f[4]) {
    f[0] = __uint_as_float(u.x << 16);
    f[1] = __uint_as_float(u.x & 0xFFFF0000u);
    f[2] = __uint_as_float(u.y << 16);
    f[3] = __uint_as_float(u.y & 0xFFFF0000u);
}

// ---------------- CSR build ----------------
__global__ void zero_deg_kernel(int* __restrict__ deg) {
    int i = blockIdx.x * blockDim.x + threadIdx.x;
    if (i < N_NODES) deg[i] = 0;
}

__global__ void count_deg_kernel(const int* __restrict__ dst, int* __restrict__ deg) {
    int e = blockIdx.x * blockDim.x + threadIdx.x;
    if (e < E_EDGES) atomicAdd(&deg[dst[e]], 1);
}

__global__ void dinv_kernel(const int* __restrict__ deg, float* __restrict__ dinv) {
    int i = blockIdx.x * blockDim.x + threadIdx.x;
    if (i < N_NODES) dinv[i] = rsqrtf((float)deg[i] + 1.0f);   // +1 self loop
}

// single-block scan: thread-serial chunk + one block scan
#define SCAN_T 1024
#define SCAN_CHUNK 49          // ceil(50000/1024)
__global__ __launch_bounds__(1024) void scan_kernel(const int* __restrict__ deg,
                                                    int* __restrict__ rowptr,
                                                    int* __restrict__ cursor) {
    __shared__ int sums[SCAN_T];
    const int t = threadIdx.x;
    const int base = t * SCAN_CHUNK;
    int local[SCAN_CHUNK];
    int s = 0;
    #pragma unroll
    for (int i = 0; i < SCAN_CHUNK; ++i) {
        int idx = base + i;
        int v = (idx < N_NODES) ? deg[idx] : 0;
        local[i] = s;
        s += v;
    }
    sums[t] = s;
    __syncthreads();
    int x = s;
    for (int off = 1; off < SCAN_T; off <<= 1) {
        int y = (t >= off) ? sums[t - off] : 0;
        __syncthreads();
        x += y;
        sums[t] = x;
        __syncthreads();
    }
    int excl = x - s;
    #pragma unroll
    for (int i = 0; i < SCAN_CHUNK; ++i) {
        int idx = base + i;
        if (idx < N_NODES) {
            int p = excl + local[i];
            rowptr[idx] = p;
            cursor[idx] = p;
        }
    }
    if (t == SCAN_T - 1) rowptr[N_NODES] = x;
}

__global__ void scatter_kernel(const int* __restrict__ src, const int* __restrict__ dst,
                               const float* __restrict__ dinv, int* __restrict__ cursor,
                               int* __restrict__ csr_src, float* __restrict__ csr_w) {
    int e = blockIdx.x * blockDim.x + threadIdx.x;
    if (e >= E_EDGES) return;
    int s = src[e], d = dst[e];
    int pos = atomicAdd(&cursor[d], 1);
    csr_src[pos] = s;
    csr_w[pos] = dinv[s] * dinv[d];
}

// ---------------- weight convert: WcatT[n][k] (n-major), W2T[n][k] ----------------
__global__ void wcvt_kernel(const float* __restrict__ W1, const float* __restrict__ Wskip,
                            const float* __restrict__ W2,
                            ushortT* __restrict__ WcatT, ushortT* __restrict__ W2T) {
    int id = blockIdx.x * blockDim.x + threadIdx.x;
    if (id < NCAT * IN_F) {
        int n = id >> 9;
        int k = id & 511;
        float v = (n < HID_F) ? W1[(size_t)k * HID_F + n]
                              : Wskip[(size_t)k * OUT_F + (n - HID_F)];
        WcatT[id] = f2bf(v);
    } else if (id < NCAT * IN_F + OUT_F * HID_F) {
        int j = id - NCAT * IN_F;
        int n = j >> 8;
        int k = j & 255;
        W2T[j] = f2bf(W2[(size_t)k * OUT_F + n]);
    }
}

// ---------------- rownorm: xb = bf16(clean(x) / max(||x||, eps)) ----------------
__global__ __launch_bounds__(256) void rownorm_kernel(const float* __restrict__ x,
                                                      ushortT* __restrict__ xb) {
    int row = blockIdx.x * 4 + (threadIdx.x >> 6);
    if (row >= N_NODES) return;
    int lane = threadIdx.x & 63;
    const float4* xr = (const float4*)(x + (size_t)row * IN_F);
    float4 v0 = xr[lane * 2];
    float4 v1 = xr[lane * 2 + 1];
    v0.x = clean0(v0.x); v0.y = clean0(v0.y); v0.z = clean0(v0.z); v0.w = clean0(v0.w);
    v1.x = clean0(v1.x); v1.y = clean0(v1.y); v1.z = clean0(v1.z); v1.w = clean0(v1.w);
    float s = v0.x*v0.x + v0.y*v0.y + v0.z*v0.z + v0.w*v0.w
            + v1.x*v1.x + v1.y*v1.y + v1.z*v1.z + v1.w*v1.w;
    #pragma unroll
    for (int off = 32; off > 0; off >>= 1) s += __shfl_xor(s, off, 64);
    float rn = 1.0f / fmaxf(sqrtf(s), L2_EPS);
    ushortT o[8];
    o[0] = f2bf(v0.x * rn); o[1] = f2bf(v0.y * rn); o[2] = f2bf(v0.z * rn); o[3] = f2bf(v0.w * rn);
    o[4] = f2bf(v1.x * rn); o[5] = f2bf(v1.y * rn); o[6] = f2bf(v1.z * rn); o[7] = f2bf(v1.w * rn);
    *(uint4*)(xb + (size_t)row * IN_F + lane * 8) = *(uint4*)o;
}

// ---------------- GEMM1 v2: [Nx512]@[512x320], one block = 128 rows x ALL 320 cols ----------------
#define G1_BM 128
#define G1_BK 64
#define PITCH 72              // bf16 elems per LDS row (144 B)
__global__ __launch_bounds__(512) void gemm1_v2_kernel(const ushortT* __restrict__ xb,
                                                       const ushortT* __restrict__ WcatT,
                                                       ushortT* __restrict__ h1b,
                                                       float* __restrict__ skip) {
    __shared__ ushortT As[G1_BM * PITCH];   // 18.4 KB
    __shared__ ushortT Bs[NCAT * PITCH];    // 46.1 KB
    const int t = threadIdx.x;
    const int lane = t & 63;
    const int wid = t >> 6;                // 8 waves
    const int wr = wid >> 2, wc = wid & 3; // wave tile 64 x 80
    const int lr = lane & 15, lk = lane >> 4;
    const int brow = blockIdx.x * G1_BM;
    const int sr = t >> 3, sl = t & 7;     // staging: row (0..63), 16B slot (0..7)

    f32x4 acc[4][5] = {};
    uint4 areg[2], breg[5];

    #pragma unroll
    for (int i = 0; i < 2; ++i) {
        int r = brow + sr + 64 * i;
        r = (r < N_NODES) ? r : (N_NODES - 1);
        areg[i] = *(const uint4*)(xb + (size_t)r * IN_F + sl * 8);
    }
    #pragma unroll
    for (int i = 0; i < 5; ++i) {
        int n = sr + 64 * i;
        breg[i] = *(const uint4*)(WcatT + (size_t)n * IN_F + sl * 8);
    }

    for (int k0 = 0; k0 < IN_F; k0 += G1_BK) {
        __syncthreads();
        #pragma unroll
        for (int i = 0; i < 2; ++i)
            *(uint4*)&As[(sr + 64 * i) * PITCH + sl * 8] = areg[i];
        #pragma unroll
        for (int i = 0; i < 5; ++i)
            *(uint4*)&Bs[(sr + 64 * i) * PITCH + sl * 8] = breg[i];
        __syncthreads();
        if (k0 + G1_BK < IN_F) {
            int kn = k0 + G1_BK;
            #pragma unroll
            for (int i = 0; i < 2; ++i) {
                int r = brow + sr + 64 * i;
                r = (r < N_NODES) ? r : (N_NODES - 1);
                areg[i] = *(const uint4*)(xb + (size_t)r * IN_F + kn + sl * 8);
            }
            #pragma unroll
            for (int i = 0; i < 5; ++i) {
                int n = sr + 64 * i;
                breg[i] = *(const uint4*)(WcatT + (size_t)n * IN_F + kn + sl * 8);
            }
        }
        #pragma unroll
        for (int kk = 0; kk < 2; ++kk) {
            short8 a[4], b[5];
            #pragma unroll
            for (int m = 0; m < 4; ++m)
                a[m] = *(const short8*)&As[(wr * 64 + m * 16 + lr) * PITCH + kk * 32 + lk * 8];
            #pragma unroll
            for (int n = 0; n < 5; ++n)
                b[n] = *(const short8*)&Bs[(wc * 80 + n * 16 + lr) * PITCH + kk * 32 + lk * 8];
            #pragma unroll
            for (int m = 0; m < 4; ++m)
                #pragma unroll
                for (int n = 0; n < 5; ++n)
                    acc[m][n] = __builtin_amdgcn_mfma_f32_16x16x32_bf16(a[m], b[n], acc[m][n], 0, 0, 0);
        }
    }

    // epilogue: row = wr*64 + m*16 + lk*4 + v ; col = wc*80 + n*16 + lr
    #pragma unroll
    for (int m = 0; m < 4; ++m) {
        int grow = brow + wr * 64 + m * 16 + lk * 4;
        #pragma unroll
        for (int n = 0; n < 5; ++n) {
            int col = wc * 80 + n * 16 + lr;
            if (col < HID_F) {
                #pragma unroll
                for (int v = 0; v < 4; ++v)
                    if (grow + v < N_NODES)
                        h1b[(size_t)(grow + v) * HID_F + col] = f2bf(acc[m][n][v]);
            } else {
                int c2 = col - HID_F;
                #pragma unroll
                for (int v = 0; v < 4; ++v)
                    if (grow + v < N_NODES)
                        skip[(size_t)(grow + v) * OUT_F + c2] = acc[m][n][v];
            }
        }
    }
}

// ---------------- fused aggregation1 + bias + LayerNorm + ReLU -> lnb (bf16) ----------------
__global__ __launch_bounds__(256) void agg1_ln_kernel(const ushortT* __restrict__ h1b,
                                                      const float* __restrict__ dinv,
                                                      const int* __restrict__ rowptr,
                                                      const int* __restrict__ csr_src,
                                                      const float* __restrict__ csr_w,
                                                      const float* __restrict__ b1,
                                                      const float* __restrict__ gamma,
                                                      const float* __restrict__ beta,
                                                      ushortT* __restrict__ lnb) {
    int node = blockIdx.x * 4 + (threadIdx.x >> 6);
    if (node >= N_NODES) return;
    int lane = threadIdx.x & 63;
    float di = dinv[node];
    float ws = di * di;
    float f[4], g0[4], g1v[4];
    uint2 u = *(const uint2*)(h1b + (size_t)node * HID_F + lane * 4);
    bf4_to_f32(u, f);
    float a0 = f[0] * ws, a1 = f[1] * ws, a2 = f[2] * ws, a3 = f[3] * ws;

    int jb = rowptr[node], je = rowptr[node + 1];
    int j = jb;
    for (; j + 1 < je; j += 2) {
        int s0 = csr_src[j];
        int s1 = csr_src[j + 1];
        float w0 = csr_w[j];
        float w1 = csr_w[j + 1];
        uint2 u0 = *(const uint2*)(h1b + (size_t)s0 * HID_F + lane * 4);
        uint2 u1 = *(const uint2*)(h1b + (size_t)s1 * HID_F + lane * 4);
        bf4_to_f32(u0, g0);
        bf4_to_f32(u1, g1v);
        a0 = fmaf(g0[0], w0, a0); a1 = fmaf(g0[1], w0, a1);
        a2 = fmaf(g0[2], w0, a2); a3 = fmaf(g0[3], w0, a3);
        a0 = fmaf(g1v[0], w1, a0); a1 = fmaf(g1v[1], w1, a1);
        a2 = fmaf(g1v[2], w1, a2); a3 = fmaf(g1v[3], w1, a3);
    }
    if (j < je) {
        int s0 = csr_src[j];
        float w0 = csr_w[j];
        uint2 u0 = *(const uint2*)(h1b + (size_t)s0 * HID_F + lane * 4);
        bf4_to_f32(u0, g0);
        a0 = fmaf(g0[0], w0, a0); a1 = fmaf(g0[1], w0, a1);
        a2 = fmaf(g0[2], w0, a2); a3 = fmaf(g0[3], w0, a3);
    }

    float4 bb = *(const float4*)(b1 + lane * 4);
    a0 += bb.x; a1 += bb.y; a2 += bb.z; a3 += bb.w;

    float s = a0 + a1 + a2 + a3;
    float s2 = a0 * a0 + a1 * a1 + a2 * a2 + a3 * a3;
    #pragma unroll
    for (int off = 32; off > 0; off >>= 1) {
        s += __shfl_xor(s, off, 64);
        s2 += __shfl_xor(s2, off, 64);
    }
    float mu = s * (1.0f / HID_F);
    float var = s2 * (1.0f / HID_F) - mu * mu;
    float rs = rsqrtf(var + LN_EPS);
    float4 gm = *(const float4*)(gamma + lane * 4);
    float4 be = *(const float4*)(beta + lane * 4);
    float y0 = fmaxf(0.0f, (a0 - mu) * rs * gm.x + be.x);
    float y1 = fmaxf(0.0f, (a1 - mu) * rs * gm.y + be.y);
    float y2 = fmaxf(0.0f, (a2 - mu) * rs * gm.z + be.z);
    float y3 = fmaxf(0.0f, (a3 - mu) * rs * gm.w + be.w);
    unsigned int lo = (unsigned int)f2bf(y0) | ((unsigned int)f2bf(y1) << 16);
    unsigned int hi = (unsigned int)f2bf(y2) | ((unsigned int)f2bf(y3) << 16);
    *(uint2*)(lnb + (size_t)node * HID_F + lane * 4) = make_uint2(lo, hi);
}

// ---------------- GEMM2 MFMA: lnb [Nx256] @ W2T -> h2 fp32 [Nx64] ----------------
__global__ __launch_bounds__(256) void gemm2_mfma_kernel(const ushortT* __restrict__ lnb,
                                                         const ushortT* __restrict__ W2T,
                                                         float* __restrict__ h2) {
    __shared__ ushortT As[G1_BM * PITCH];   // 18.4 KB (128 rows)
    __shared__ ushortT Bs[OUT_F * PITCH];   // 9.2 KB (64 rows)
    const int t = threadIdx.x;
    const int lane = t & 63;
    const int wid = t >> 6;                // 4 waves
    const int wr = wid >> 1, wc = wid & 1; // wave tile 64 x 32
    const int lr = lane & 15, lk = lane >> 4;
    const int brow = blockIdx.x * G1_BM;
    const int sr = t >> 3, sl = t & 7;     // staging row (0..31), slot

    f32x4 acc[4][2] = {};
    uint4 areg[4], breg[2];

    #pragma unroll
    for (int i = 0; i < 4; ++i) {
        int r = brow + sr + 32 * i;
        r = (r < N_NODES) ? r : (N_NODES - 1);
        areg[i] = *(const uint4*)(lnb + (size_t)r * HID_F + sl * 8);
    }
    #pragma unroll
    for (int i = 0; i < 2; ++i) {
        int n = sr + 32 * i;
        breg[i] = *(const uint4*)(W2T + (size_t)n * HID_F + sl * 8);
    }

    for (int k0 = 0; k0 < HID_F; k0 += G1_BK) {
        __syncthreads();
        #pragma unroll
        for (int i = 0; i < 4; ++i)
            *(uint4*)&As[(sr + 32 * i) * PITCH + sl * 8] = areg[i];
        #pragma unroll
        for (int i = 0; i < 2; ++i)
            *(uint4*)&Bs[(sr + 32 * i) * PITCH + sl * 8] = breg[i];
        __syncthreads();
        if (k0 + G1_BK < HID_F) {
            int kn = k0 + G1_BK;
            #pragma unroll
            for (int i = 0; i < 4; ++i) {
                int r = brow + sr + 32 * i;
                r = (r < N_NODES) ? r : (N_NODES - 1);
                areg[i] = *(const uint4*)(lnb + (size_t)r * HID_F + kn + sl * 8);
            }
            #pragma unroll
            for (int i = 0; i < 2; ++i) {
                int n = sr + 32 * i;
                breg[i] = *(const uint4*)(W2T + (size_t)n * HID_F + kn + sl * 8);
            }
        }
        #pragma unroll
        for (int kk = 0; kk < 2; ++kk) {
            short8 a[4], b[2];
            #pragma unroll
            for (int m = 0; m < 4; ++m)
                a[m] = *(const short8*)&As[(wr * 64 + m * 16 + lr) * PITCH + kk * 32 + lk * 8];
            #pragma unroll
            for (int n = 0; n < 2; ++n)
                b[n] = *(const short8*)&Bs[(wc * 32 + n * 16 + lr) * PITCH + kk * 32 + lk * 8];
            #pragma unroll
            for (int m = 0; m < 4; ++m)
                #pragma unroll
                for (int n = 0; n < 2; ++n)
                    acc[m][n] = __builtin_amdgcn_mfma_f32_16x16x32_bf16(a[m], b[n], acc[m][n], 0, 0, 0);
        }
    }

    #pragma unroll
    for (int m = 0; m < 4; ++m) {
        int grow = brow + wr * 64 + m * 16 + lk * 4;
        #pragma unroll
        for (int v = 0; v < 4; ++v) {
            if (grow + v < N_NODES) {
                float* rowp = h2 + (size_t)(grow + v) * OUT_F + wc * 32 + lr;
                rowp[0]  = acc[m][0][v];
                rowp[16] = acc[m][1][v];
            }
        }
    }
}

// ---------------- aggregation 2: CSR gather + skip + b2 + nan_to_num -> out ----------------
__global__ __launch_bounds__(256) void agg2_gather_kernel(const float* __restrict__ h2,
                                                          const float* __restrict__ skip,
                                                          const float* __restrict__ b2,
                                                          const float* __restrict__ dinv,
                                                          const int* __restrict__ rowptr,
                                                          const int* __restrict__ csr_src,
                                                          const float* __restrict__ csr_w,
                                                          float* __restrict__ out) {
    int node = blockIdx.x * 4 + (threadIdx.x >> 6);
    if (node >= N_NODES) return;
    int lane = threadIdx.x & 63;
    float di = dinv[node];
    float acc = h2[(size_t)node * OUT_F + lane] * di * di;
    int jb = rowptr[node], je = rowptr[node + 1];
    int j = jb;
    for (; j + 1 < je; j += 2) {
        int s0 = csr_src[j];
        int s1 = csr_src[j + 1];
        float w0 = csr_w[j];
        float w1 = csr_w[j + 1];
        float v0 = h2[(size_t)s0 * OUT_F + lane];
        float v1 = h2[(size_t)s1 * OUT_F + lane];
        acc = fmaf(v0, w0, acc);
        acc = fmaf(v1, w1, acc);
    }
    if (j < je) {
        acc = fmaf(h2[(size_t)csr_src[j] * OUT_F + lane], csr_w[j], acc);
    }
    float v = acc + skip[(size_t)node * OUT_F + lane] + b2[lane];
    if (isnan(v)) v = 0.0f;
    else if (isinf(v)) v = (v > 0.0f) ? 20.0f : -20.0f;
    out[(size_t)node * OUT_F + lane] = v;
}

extern "C" void kernel_launch(void* const* d_in, const int* in_sizes, int n_in,
                              void* d_out, int out_size, void* d_ws, size_t ws_size,
                              hipStream_t stream) {
    const float* x     = (const float*)d_in[0];
    const int*   ei    = (const int*)d_in[1];
    const float* W1    = (const float*)d_in[2];
    const float* b1    = (const float*)d_in[3];
    const float* gamma = (const float*)d_in[4];
    const float* beta  = (const float*)d_in[5];
    const float* W2    = (const float*)d_in[6];
    const float* b2    = (const float*)d_in[7];
    const float* Wskip = (const float*)d_in[8];
    float* out = (float*)d_out;

    const int* src = ei;
    const int* dst = ei + E_EDGES;

    // ws layout
    ushortT* xb    = (ushortT*)d_ws;                       // N*512 bf16 (51.2MB)
    ushortT* lnb   = xb;                                   // overlays xb after gemm1 (N*256)
    ushortT* h1b   = xb + (size_t)N_NODES * IN_F;          // N*256 bf16
    float* h2      = (float*)(h1b + (size_t)N_NODES * HID_F);  // N*64 f32
    float* skip    = h2 + (size_t)N_NODES * OUT_F;         // N*64 f32
    float* dinv    = skip + (size_t)N_NODES * OUT_F;       // N
    float* csr_w   = dinv + N_NODES;                       // E
    ushortT* WcatT = (ushortT*)(csr_w + E_EDGES);          // 320*512
    ushortT* W2T   = WcatT + (size_t)NCAT * IN_F;          // 64*256
    int* deg       = (int*)(W2T + (size_t)OUT_F * HID_F);  // N
    int* rowptr    = deg + N_NODES;                        // N+1
    int* cursor    = rowptr + N_NODES + 1;                 // N
    int* csr_src   = cursor + N_NODES;                     // E

    // ---- CSR build + dinv ----
    zero_deg_kernel<<<(N_NODES + 255) / 256, 256, 0, stream>>>(deg);
    count_deg_kernel<<<(E_EDGES + 255) / 256, 256, 0, stream>>>(dst, deg);
    dinv_kernel<<<(N_NODES + 255) / 256, 256, 0, stream>>>(deg, dinv);
    scan_kernel<<<1, SCAN_T, 0, stream>>>(deg, rowptr, cursor);
    scatter_kernel<<<(E_EDGES + 255) / 256, 256, 0, stream>>>(src, dst, dinv, cursor,
                                                              csr_src, csr_w);

    // ---- weight convert + row norm ----
    wcvt_kernel<<<(NCAT * IN_F + OUT_F * HID_F + 255) / 256, 256, 0, stream>>>(
        W1, Wskip, W2, WcatT, W2T);
    rownorm_kernel<<<(N_NODES + 3) / 4, 256, 0, stream>>>(x, xb);

    // ---- GEMM1 v2 (h1b bf16 + skip fp32), single pass over xb ----
    gemm1_v2_kernel<<<(N_NODES + G1_BM - 1) / G1_BM, 512, 0, stream>>>(xb, WcatT, h1b, skip);

    // ---- fused agg1 + bias + LN + ReLU -> lnb (overwrites xb region; xb dead) ----
    agg1_ln_kernel<<<(N_NODES + 3) / 4, 256, 0, stream>>>(h1b, dinv, rowptr, csr_src,
                                                          csr_w, b1, gamma, beta, lnb);

    // ---- GEMM2 MFMA ----
    gemm2_mfma_kernel<<<(N_NODES + G1_BM - 1) / G1_BM, 256, 0, stream>>>(lnb, W2T, h2);

    // ---- aggregation 2 (CSR gather, fused epilogue) ----
    agg2_gather_kernel<<<(N_NODES + 3) / 4, 256, 0, stream>>>(h2, skip, b2, dinv, rowptr,
                                                              csr_src, csr_w, out);
}

// Round 5
// 423.366 us; speedup vs baseline: 8.8538x; 1.0136x over previous
//
#include <hip/hip_runtime.h>
#include <hip/hip_bf16.h>
#include <cstddef>

#define N_NODES 50000
#define E_EDGES 800000
#define IN_F 512
#define HID_F 256
#define OUT_F 64
#define NCAT 320              // HID + OUT combined GEMM1 output cols
#define LN_EPS 1e-5f
#define L2_EPS 1e-12f

typedef unsigned short ushortT;
typedef __attribute__((ext_vector_type(8))) short short8;
typedef __attribute__((ext_vector_type(4))) float f32x4;

static __device__ __forceinline__ float clean0(float v) {
    return isfinite(v) ? v : 0.0f;
}

static __device__ __forceinline__ ushortT f2bf(float f) {
    __hip_bfloat16 h = __float2bfloat16(f);
    return *reinterpret_cast<ushortT*>(&h);
}

static __device__ __forceinline__ void bf4_to_f32(uint2 u, float f[4]) {
    f[0] = __uint_as_float(u.x << 16);
    f[1] = __uint_as_float(u.x & 0xFFFF0000u);
    f[2] = __uint_as_float(u.y << 16);
    f[3] = __uint_as_float(u.y & 0xFFFF0000u);
}

// ---------------- CSR build ----------------
__global__ void zero_deg_kernel(int* __restrict__ deg) {
    int i = blockIdx.x * blockDim.x + threadIdx.x;
    if (i < N_NODES) deg[i] = 0;
}

__global__ void count_deg_kernel(const int* __restrict__ dst, int* __restrict__ deg) {
    int e = blockIdx.x * blockDim.x + threadIdx.x;
    if (e < E_EDGES) atomicAdd(&deg[dst[e]], 1);
}

__global__ void dinv_kernel(const int* __restrict__ deg, float* __restrict__ dinv) {
    int i = blockIdx.x * blockDim.x + threadIdx.x;
    if (i < N_NODES) dinv[i] = rsqrtf((float)deg[i] + 1.0f);   // +1 self loop
}

// single-block scan: thread-serial chunk + one block scan
#define SCAN_T 1024
#define SCAN_CHUNK 49          // ceil(50000/1024)
__global__ __launch_bounds__(1024) void scan_kernel(const int* __restrict__ deg,
                                                    int* __restrict__ rowptr,
                                                    int* __restrict__ cursor) {
    __shared__ int sums[SCAN_T];
    const int t = threadIdx.x;
    const int base = t * SCAN_CHUNK;
    int local[SCAN_CHUNK];
    int s = 0;
    #pragma unroll
    for (int i = 0; i < SCAN_CHUNK; ++i) {
        int idx = base + i;
        int v = (idx < N_NODES) ? deg[idx] : 0;
        local[i] = s;
        s += v;
    }
    sums[t] = s;
    __syncthreads();
    int x = s;
    for (int off = 1; off < SCAN_T; off <<= 1) {
        int y = (t >= off) ? sums[t - off] : 0;
        __syncthreads();
        x += y;
        sums[t] = x;
        __syncthreads();
    }
    int excl = x - s;
    #pragma unroll
    for (int i = 0; i < SCAN_CHUNK; ++i) {
        int idx = base + i;
        if (idx < N_NODES) {
            int p = excl + local[i];
            rowptr[idx] = p;
            cursor[idx] = p;
        }
    }
    if (t == SCAN_T - 1) rowptr[N_NODES] = x;
}

__global__ void scatter_kernel(const int* __restrict__ src, const int* __restrict__ dst,
                               const float* __restrict__ dinv, int* __restrict__ cursor,
                               int* __restrict__ csr_src, float* __restrict__ csr_w) {
    int e = blockIdx.x * blockDim.x + threadIdx.x;
    if (e >= E_EDGES) return;
    int s = src[e], d = dst[e];
    int pos = atomicAdd(&cursor[d], 1);
    csr_src[pos] = s;
    csr_w[pos] = dinv[s] * dinv[d];
}

// ---------------- weight convert: WcatT[n][k] (n-major), W2T[n][k] ----------------
__global__ void wcvt_kernel(const float* __restrict__ W1, const float* __restrict__ Wskip,
                            const float* __restrict__ W2,
                            ushortT* __restrict__ WcatT, ushortT* __restrict__ W2T) {
    int id = blockIdx.x * blockDim.x + threadIdx.x;
    if (id < NCAT * IN_F) {
        int n = id >> 9;
        int k = id & 511;
        float v = (n < HID_F) ? W1[(size_t)k * HID_F + n]
                              : Wskip[(size_t)k * OUT_F + (n - HID_F)];
        WcatT[id] = f2bf(v);
    } else if (id < NCAT * IN_F + OUT_F * HID_F) {
        int j = id - NCAT * IN_F;
        int n = j >> 8;
        int k = j & 255;
        W2T[j] = f2bf(W2[(size_t)k * OUT_F + n]);
    }
}

// ---------------- rownorm: xb = bf16(clean(x) / max(||x||, eps)) ----------------
__global__ __launch_bounds__(256) void rownorm_kernel(const float* __restrict__ x,
                                                      ushortT* __restrict__ xb) {
    int row = blockIdx.x * 4 + (threadIdx.x >> 6);
    if (row >= N_NODES) return;
    int lane = threadIdx.x & 63;
    const float4* xr = (const float4*)(x + (size_t)row * IN_F);
    float4 v0 = xr[lane * 2];
    float4 v1 = xr[lane * 2 + 1];
    v0.x = clean0(v0.x); v0.y = clean0(v0.y); v0.z = clean0(v0.z); v0.w = clean0(v0.w);
    v1.x = clean0(v1.x); v1.y = clean0(v1.y); v1.z = clean0(v1.z); v1.w = clean0(v1.w);
    float s = v0.x*v0.x + v0.y*v0.y + v0.z*v0.z + v0.w*v0.w
            + v1.x*v1.x + v1.y*v1.y + v1.z*v1.z + v1.w*v1.w;
    #pragma unroll
    for (int off = 32; off > 0; off >>= 1) s += __shfl_xor(s, off, 64);
    float rn = 1.0f / fmaxf(sqrtf(s), L2_EPS);
    ushortT o[8];
    o[0] = f2bf(v0.x * rn); o[1] = f2bf(v0.y * rn); o[2] = f2bf(v0.z * rn); o[3] = f2bf(v0.w * rn);
    o[4] = f2bf(v1.x * rn); o[5] = f2bf(v1.y * rn); o[6] = f2bf(v1.z * rn); o[7] = f2bf(v1.w * rn);
    *(uint4*)(xb + (size_t)row * IN_F + lane * 8) = *(uint4*)o;
}

// ---------------- GEMM1 v3: BM=64, all 320 cols, 8 waves (2x4), wave tile 32x80 ----------------
#define G1_BM 64
#define G1_BK 64
#define PITCH 72              // bf16 elems per LDS row (144 B)
__global__ __launch_bounds__(512) void gemm1_v3_kernel(const ushortT* __restrict__ xb,
                                                       const ushortT* __restrict__ WcatT,
                                                       ushortT* __restrict__ h1b,
                                                       float* __restrict__ skip) {
    __shared__ ushortT As[G1_BM * PITCH];   // 9.2 KB
    __shared__ ushortT Bs[NCAT * PITCH];    // 46.1 KB
    const int t = threadIdx.x;
    const int lane = t & 63;
    const int wid = t >> 6;                // 8 waves
    const int wr = wid >> 2, wc = wid & 3; // 2 row-waves x 4 col-waves; wave tile 32x80
    const int lr = lane & 15, lk = lane >> 4;
    const int brow = blockIdx.x * G1_BM;
    const int sr = t >> 3, sl = t & 7;     // staging: row (0..63), 16B slot (0..7)

    f32x4 acc[2][5] = {};
    uint4 areg;
    uint4 breg[5];

    {
        int r = brow + sr;
        r = (r < N_NODES) ? r : (N_NODES - 1);
        areg = *(const uint4*)(xb + (size_t)r * IN_F + sl * 8);
        #pragma unroll
        for (int i = 0; i < 5; ++i)
            breg[i] = *(const uint4*)(WcatT + (size_t)(sr + 64 * i) * IN_F + sl * 8);
    }

    for (int k0 = 0; k0 < IN_F; k0 += G1_BK) {
        __syncthreads();
        *(uint4*)&As[sr * PITCH + sl * 8] = areg;
        #pragma unroll
        for (int i = 0; i < 5; ++i)
            *(uint4*)&Bs[(sr + 64 * i) * PITCH + sl * 8] = breg[i];
        __syncthreads();
        if (k0 + G1_BK < IN_F) {
            int kn = k0 + G1_BK;
            int r = brow + sr;
            r = (r < N_NODES) ? r : (N_NODES - 1);
            areg = *(const uint4*)(xb + (size_t)r * IN_F + kn + sl * 8);
            #pragma unroll
            for (int i = 0; i < 5; ++i)
                breg[i] = *(const uint4*)(WcatT + (size_t)(sr + 64 * i) * IN_F + kn + sl * 8);
        }
        #pragma unroll
        for (int kk = 0; kk < 2; ++kk) {
            short8 a[2], b[5];
            #pragma unroll
            for (int m = 0; m < 2; ++m)
                a[m] = *(const short8*)&As[(wr * 32 + m * 16 + lr) * PITCH + kk * 32 + lk * 8];
            #pragma unroll
            for (int n = 0; n < 5; ++n)
                b[n] = *(const short8*)&Bs[(wc * 80 + n * 16 + lr) * PITCH + kk * 32 + lk * 8];
            #pragma unroll
            for (int m = 0; m < 2; ++m)
                #pragma unroll
                for (int n = 0; n < 5; ++n)
                    acc[m][n] = __builtin_amdgcn_mfma_f32_16x16x32_bf16(a[m], b[n], acc[m][n], 0, 0, 0);
        }
    }

    // epilogue: row = wr*32 + m*16 + lk*4 + v ; col = wc*80 + n*16 + lr
    #pragma unroll
    for (int m = 0; m < 2; ++m) {
        int grow = brow + wr * 32 + m * 16 + lk * 4;
        #pragma unroll
        for (int n = 0; n < 5; ++n) {
            int col = wc * 80 + n * 16 + lr;
            if (col < HID_F) {
                #pragma unroll
                for (int v = 0; v < 4; ++v)
                    if (grow + v < N_NODES)
                        h1b[(size_t)(grow + v) * HID_F + col] = f2bf(acc[m][n][v]);
            } else {
                int c2 = col - HID_F;
                #pragma unroll
                for (int v = 0; v < 4; ++v)
                    if (grow + v < N_NODES)
                        skip[(size_t)(grow + v) * OUT_F + c2] = acc[m][n][v];
            }
        }
    }
}

// ---------------- fused aggregation1 + bias + LayerNorm + ReLU -> lnb (bf16) ----------------
__global__ __launch_bounds__(256) void agg1_ln_kernel(const ushortT* __restrict__ h1b,
                                                      const float* __restrict__ dinv,
                                                      const int* __restrict__ rowptr,
                                                      const int* __restrict__ csr_src,
                                                      const float* __restrict__ csr_w,
                                                      const float* __restrict__ b1,
                                                      const float* __restrict__ gamma,
                                                      const float* __restrict__ beta,
                                                      ushortT* __restrict__ lnb) {
    int node = blockIdx.x * 4 + (threadIdx.x >> 6);
    if (node >= N_NODES) return;
    int lane = threadIdx.x & 63;
    float di = dinv[node];
    float ws = di * di;
    float f[4];
    uint2 u = *(const uint2*)(h1b + (size_t)node * HID_F + lane * 4);
    bf4_to_f32(u, f);
    float a0 = f[0] * ws, a1 = f[1] * ws, a2 = f[2] * ws, a3 = f[3] * ws;

    int jb = rowptr[node], je = rowptr[node + 1];
    int j = jb;
    for (; j + 3 < je; j += 4) {
        int s0 = csr_src[j];
        int s1 = csr_src[j + 1];
        int s2 = csr_src[j + 2];
        int s3 = csr_src[j + 3];
        float w0 = csr_w[j];
        float w1 = csr_w[j + 1];
        float w2 = csr_w[j + 2];
        float w3 = csr_w[j + 3];
        uint2 u0 = *(const uint2*)(h1b + (size_t)s0 * HID_F + lane * 4);
        uint2 u1 = *(const uint2*)(h1b + (size_t)s1 * HID_F + lane * 4);
        uint2 u2 = *(const uint2*)(h1b + (size_t)s2 * HID_F + lane * 4);
        uint2 u3 = *(const uint2*)(h1b + (size_t)s3 * HID_F + lane * 4);
        float g0[4], g1[4], g2[4], g3[4];
        bf4_to_f32(u0, g0); bf4_to_f32(u1, g1); bf4_to_f32(u2, g2); bf4_to_f32(u3, g3);
        a0 = fmaf(g0[0], w0, a0); a1 = fmaf(g0[1], w0, a1);
        a2 = fmaf(g0[2], w0, a2); a3 = fmaf(g0[3], w0, a3);
        a0 = fmaf(g1[0], w1, a0); a1 = fmaf(g1[1], w1, a1);
        a2 = fmaf(g1[2], w1, a2); a3 = fmaf(g1[3], w1, a3);
        a0 = fmaf(g2[0], w2, a0); a1 = fmaf(g2[1], w2, a1);
        a2 = fmaf(g2[2], w2, a2); a3 = fmaf(g2[3], w2, a3);
        a0 = fmaf(g3[0], w3, a0); a1 = fmaf(g3[1], w3, a1);
        a2 = fmaf(g3[2], w3, a2); a3 = fmaf(g3[3], w3, a3);
    }
    for (; j < je; ++j) {
        int s0 = csr_src[j];
        float w0 = csr_w[j];
        uint2 u0 = *(const uint2*)(h1b + (size_t)s0 * HID_F + lane * 4);
        float g0[4];
        bf4_to_f32(u0, g0);
        a0 = fmaf(g0[0], w0, a0); a1 = fmaf(g0[1], w0, a1);
        a2 = fmaf(g0[2], w0, a2); a3 = fmaf(g0[3], w0, a3);
    }

    float4 bb = *(const float4*)(b1 + lane * 4);
    a0 += bb.x; a1 += bb.y; a2 += bb.z; a3 += bb.w;

    float s = a0 + a1 + a2 + a3;
    float s2 = a0 * a0 + a1 * a1 + a2 * a2 + a3 * a3;
    #pragma unroll
    for (int off = 32; off > 0; off >>= 1) {
        s += __shfl_xor(s, off, 64);
        s2 += __shfl_xor(s2, off, 64);
    }
    float mu = s * (1.0f / HID_F);
    float var = s2 * (1.0f / HID_F) - mu * mu;
    float rs = rsqrtf(var + LN_EPS);
    float4 gm = *(const float4*)(gamma + lane * 4);
    float4 be = *(const float4*)(beta + lane * 4);
    float y0 = fmaxf(0.0f, (a0 - mu) * rs * gm.x + be.x);
    float y1 = fmaxf(0.0f, (a1 - mu) * rs * gm.y + be.y);
    float y2 = fmaxf(0.0f, (a2 - mu) * rs * gm.z + be.z);
    float y3 = fmaxf(0.0f, (a3 - mu) * rs * gm.w + be.w);
    unsigned int lo = (unsigned int)f2bf(y0) | ((unsigned int)f2bf(y1) << 16);
    unsigned int hi = (unsigned int)f2bf(y2) | ((unsigned int)f2bf(y3) << 16);
    *(uint2*)(lnb + (size_t)node * HID_F + lane * 4) = make_uint2(lo, hi);
}

// ---------------- GEMM2 v2: BM=64, 4 waves (2x2), wave tile 32x32 ----------------
__global__ __launch_bounds__(256) void gemm2_v2_kernel(const ushortT* __restrict__ lnb,
                                                       const ushortT* __restrict__ W2T,
                                                       float* __restrict__ h2) {
    __shared__ ushortT As[G1_BM * PITCH];   // 9.2 KB
    __shared__ ushortT Bs[OUT_F * PITCH];   // 9.2 KB
    const int t = threadIdx.x;
    const int lane = t & 63;
    const int wid = t >> 6;                // 4 waves
    const int wr = wid >> 1, wc = wid & 1; // 2x2, wave tile 32x32
    const int lr = lane & 15, lk = lane >> 4;
    const int brow = blockIdx.x * G1_BM;
    const int sr = t >> 3, sl = t & 7;     // staging: row (0..31), slot

    f32x4 acc[2][2] = {};
    uint4 areg[2], breg[2];

    #pragma unroll
    for (int i = 0; i < 2; ++i) {
        int r = brow + sr + 32 * i;
        r = (r < N_NODES) ? r : (N_NODES - 1);
        areg[i] = *(const uint4*)(lnb + (size_t)r * HID_F + sl * 8);
        breg[i] = *(const uint4*)(W2T + (size_t)(sr + 32 * i) * HID_F + sl * 8);
    }

    for (int k0 = 0; k0 < HID_F; k0 += G1_BK) {
        __syncthreads();
        #pragma unroll
        for (int i = 0; i < 2; ++i) {
            *(uint4*)&As[(sr + 32 * i) * PITCH + sl * 8] = areg[i];
            *(uint4*)&Bs[(sr + 32 * i) * PITCH + sl * 8] = breg[i];
        }
        __syncthreads();
        if (k0 + G1_BK < HID_F) {
            int kn = k0 + G1_BK;
            #pragma unroll
            for (int i = 0; i < 2; ++i) {
                int r = brow + sr + 32 * i;
                r = (r < N_NODES) ? r : (N_NODES - 1);
                areg[i] = *(const uint4*)(lnb + (size_t)r * HID_F + kn + sl * 8);
                breg[i] = *(const uint4*)(W2T + (size_t)(sr + 32 * i) * HID_F + kn + sl * 8);
            }
        }
        #pragma unroll
        for (int kk = 0; kk < 2; ++kk) {
            short8 a[2], b[2];
            #pragma unroll
            for (int m = 0; m < 2; ++m)
                a[m] = *(const short8*)&As[(wr * 32 + m * 16 + lr) * PITCH + kk * 32 + lk * 8];
            #pragma unroll
            for (int n = 0; n < 2; ++n)
                b[n] = *(const short8*)&Bs[(wc * 32 + n * 16 + lr) * PITCH + kk * 32 + lk * 8];
            #pragma unroll
            for (int m = 0; m < 2; ++m)
                #pragma unroll
                for (int n = 0; n < 2; ++n)
                    acc[m][n] = __builtin_amdgcn_mfma_f32_16x16x32_bf16(a[m], b[n], acc[m][n], 0, 0, 0);
        }
    }

    #pragma unroll
    for (int m = 0; m < 2; ++m) {
        int grow = brow + wr * 32 + m * 16 + lk * 4;
        #pragma unroll
        for (int v = 0; v < 4; ++v) {
            if (grow + v < N_NODES) {
                float* rowp = h2 + (size_t)(grow + v) * OUT_F + wc * 32 + lr;
                rowp[0]  = acc[m][0][v];
                rowp[16] = acc[m][1][v];
            }
        }
    }
}

// ---------------- aggregation 2: CSR gather + skip + b2 + nan_to_num -> out ----------------
__global__ __launch_bounds__(256) void agg2_gather_kernel(const float* __restrict__ h2,
                                                          const float* __restrict__ skip,
                                                          const float* __restrict__ b2,
                                                          const float* __restrict__ dinv,
                                                          const int* __restrict__ rowptr,
                                                          const int* __restrict__ csr_src,
                                                          const float* __restrict__ csr_w,
                                                          float* __restrict__ out) {
    int node = blockIdx.x * 4 + (threadIdx.x >> 6);
    if (node >= N_NODES) return;
    int lane = threadIdx.x & 63;
    float di = dinv[node];
    float acc = h2[(size_t)node * OUT_F + lane] * di * di;
    int jb = rowptr[node], je = rowptr[node + 1];
    int j = jb;
    for (; j + 3 < je; j += 4) {
        int s0 = csr_src[j];
        int s1 = csr_src[j + 1];
        int s2 = csr_src[j + 2];
        int s3 = csr_src[j + 3];
        float w0 = csr_w[j];
        float w1 = csr_w[j + 1];
        float w2 = csr_w[j + 2];
        float w3 = csr_w[j + 3];
        float v0 = h2[(size_t)s0 * OUT_F + lane];
        float v1 = h2[(size_t)s1 * OUT_F + lane];
        float v2 = h2[(size_t)s2 * OUT_F + lane];
        float v3 = h2[(size_t)s3 * OUT_F + lane];
        acc = fmaf(v0, w0, acc);
        acc = fmaf(v1, w1, acc);
        acc = fmaf(v2, w2, acc);
        acc = fmaf(v3, w3, acc);
    }
    for (; j < je; ++j) {
        acc = fmaf(h2[(size_t)csr_src[j] * OUT_F + lane], csr_w[j], acc);
    }
    float v = acc + skip[(size_t)node * OUT_F + lane] + b2[lane];
    if (isnan(v)) v = 0.0f;
    else if (isinf(v)) v = (v > 0.0f) ? 20.0f : -20.0f;
    out[(size_t)node * OUT_F + lane] = v;
}

extern "C" void kernel_launch(void* const* d_in, const int* in_sizes, int n_in,
                              void* d_out, int out_size, void* d_ws, size_t ws_size,
                              hipStream_t stream) {
    const float* x     = (const float*)d_in[0];
    const int*   ei    = (const int*)d_in[1];
    const float* W1    = (const float*)d_in[2];
    const float* b1    = (const float*)d_in[3];
    const float* gamma = (const float*)d_in[4];
    const float* beta  = (const float*)d_in[5];
    const float* W2    = (const float*)d_in[6];
    const float* b2    = (const float*)d_in[7];
    const float* Wskip = (const float*)d_in[8];
    float* out = (float*)d_out;

    const int* src = ei;
    const int* dst = ei + E_EDGES;

    // ws layout
    ushortT* xb    = (ushortT*)d_ws;                       // N*512 bf16 (51.2MB)
    ushortT* lnb   = xb;                                   // overlays xb after gemm1 (N*256)
    ushortT* h1b   = xb + (size_t)N_NODES * IN_F;          // N*256 bf16
    float* h2      = (float*)(h1b + (size_t)N_NODES * HID_F);  // N*64 f32
    float* skip    = h2 + (size_t)N_NODES * OUT_F;         // N*64 f32
    float* dinv    = skip + (size_t)N_NODES * OUT_F;       // N
    float* csr_w   = dinv + N_NODES;                       // E
    ushortT* WcatT = (ushortT*)(csr_w + E_EDGES);          // 320*512
    ushortT* W2T   = WcatT + (size_t)NCAT * IN_F;          // 64*256
    int* deg       = (int*)(W2T + (size_t)OUT_F * HID_F);  // N
    int* rowptr    = deg + N_NODES;                        // N+1
    int* cursor    = rowptr + N_NODES + 1;                 // N
    int* csr_src   = cursor + N_NODES;                     // E

    // ---- CSR build + dinv ----
    zero_deg_kernel<<<(N_NODES + 255) / 256, 256, 0, stream>>>(deg);
    count_deg_kernel<<<(E_EDGES + 255) / 256, 256, 0, stream>>>(dst, deg);
    dinv_kernel<<<(N_NODES + 255) / 256, 256, 0, stream>>>(deg, dinv);
    scan_kernel<<<1, SCAN_T, 0, stream>>>(deg, rowptr, cursor);
    scatter_kernel<<<(E_EDGES + 255) / 256, 256, 0, stream>>>(src, dst, dinv, cursor,
                                                              csr_src, csr_w);

    // ---- weight convert + row norm ----
    wcvt_kernel<<<(NCAT * IN_F + OUT_F * HID_F + 255) / 256, 256, 0, stream>>>(
        W1, Wskip, W2, WcatT, W2T);
    rownorm_kernel<<<(N_NODES + 3) / 4, 256, 0, stream>>>(x, xb);

    // ---- GEMM1 v3 (h1b bf16 + skip fp32), single pass over xb, 782 blocks ----
    gemm1_v3_kernel<<<(N_NODES + G1_BM - 1) / G1_BM, 512, 0, stream>>>(xb, WcatT, h1b, skip);

    // ---- fused agg1 + bias + LN + ReLU -> lnb (overwrites xb region; xb dead) ----
    agg1_ln_kernel<<<(N_NODES + 3) / 4, 256, 0, stream>>>(h1b, dinv, rowptr, csr_src,
                                                          csr_w, b1, gamma, beta, lnb);

    // ---- GEMM2 v2 ----
    gemm2_v2_kernel<<<(N_NODES + G1_BM - 1) / G1_BM, 256, 0, stream>>>(lnb, W2T, h2);

    // ---- aggregation 2 (CSR gather, fused epilogue) ----
    agg2_gather_kernel<<<(N_NODES + 3) / 4, 256, 0, stream>>>(h2, skip, b2, dinv, rowptr,
                                                              csr_src, csr_w, out);
}

// Round 6
// 395.475 us; speedup vs baseline: 9.4783x; 1.0705x over previous
//
#include <hip/hip_runtime.h>
#include <hip/hip_bf16.h>
#include <cstddef>

#define N_NODES 50000
#define E_EDGES 800000
#define IN_F 512
#define HID_F 256
#define OUT_F 64
#define NCAT 320              // HID + OUT combined GEMM1 output cols
#define LN_EPS 1e-5f
#define L2_EPS 1e-12f

typedef unsigned short ushortT;
typedef __attribute__((ext_vector_type(8))) short short8;
typedef __attribute__((ext_vector_type(4))) float f32x4;

static __device__ __forceinline__ float clean0(float v) {
    return isfinite(v) ? v : 0.0f;
}

static __device__ __forceinline__ ushortT f2bf(float f) {
    __hip_bfloat16 h = __float2bfloat16(f);
    return *reinterpret_cast<ushortT*>(&h);
}

static __device__ __forceinline__ void bf8_to_f32(uint4 u, float f[8]) {
    f[0] = __uint_as_float(u.x << 16);
    f[1] = __uint_as_float(u.x & 0xFFFF0000u);
    f[2] = __uint_as_float(u.y << 16);
    f[3] = __uint_as_float(u.y & 0xFFFF0000u);
    f[4] = __uint_as_float(u.z << 16);
    f[5] = __uint_as_float(u.z & 0xFFFF0000u);
    f[6] = __uint_as_float(u.w << 16);
    f[7] = __uint_as_float(u.w & 0xFFFF0000u);
}

// ---------------- CSR build ----------------
__global__ void zero_deg_kernel(int* __restrict__ deg) {
    int i = blockIdx.x * blockDim.x + threadIdx.x;
    if (i < N_NODES) deg[i] = 0;
}

__global__ void count_deg_kernel(const int* __restrict__ dst, int* __restrict__ deg) {
    int e = blockIdx.x * blockDim.x + threadIdx.x;
    if (e < E_EDGES) atomicAdd(&deg[dst[e]], 1);
}

__global__ void dinv_kernel(const int* __restrict__ deg, float* __restrict__ dinv) {
    int i = blockIdx.x * blockDim.x + threadIdx.x;
    if (i < N_NODES) dinv[i] = rsqrtf((float)deg[i] + 1.0f);   // +1 self loop
}

// single-block scan: thread-serial chunk + one block scan
#define SCAN_T 1024
#define SCAN_CHUNK 49          // ceil(50000/1024)
__global__ __launch_bounds__(1024) void scan_kernel(const int* __restrict__ deg,
                                                    int* __restrict__ rowptr,
                                                    int* __restrict__ cursor) {
    __shared__ int sums[SCAN_T];
    const int t = threadIdx.x;
    const int base = t * SCAN_CHUNK;
    int local[SCAN_CHUNK];
    int s = 0;
    #pragma unroll
    for (int i = 0; i < SCAN_CHUNK; ++i) {
        int idx = base + i;
        int v = (idx < N_NODES) ? deg[idx] : 0;
        local[i] = s;
        s += v;
    }
    sums[t] = s;
    __syncthreads();
    int x = s;
    for (int off = 1; off < SCAN_T; off <<= 1) {
        int y = (t >= off) ? sums[t - off] : 0;
        __syncthreads();
        x += y;
        sums[t] = x;
        __syncthreads();
    }
    int excl = x - s;
    #pragma unroll
    for (int i = 0; i < SCAN_CHUNK; ++i) {
        int idx = base + i;
        if (idx < N_NODES) {
            int p = excl + local[i];
            rowptr[idx] = p;
            cursor[idx] = p;
        }
    }
    if (t == SCAN_T - 1) rowptr[N_NODES] = x;
}

__global__ void scatter_kernel(const int* __restrict__ src, const int* __restrict__ dst,
                               const float* __restrict__ dinv, int* __restrict__ cursor,
                               int* __restrict__ csr_src, float* __restrict__ csr_w) {
    int e = blockIdx.x * blockDim.x + threadIdx.x;
    if (e >= E_EDGES) return;
    int s = src[e], d = dst[e];
    int pos = atomicAdd(&cursor[d], 1);
    csr_src[pos] = s;
    csr_w[pos] = dinv[s] * dinv[d];
}

// ---------------- weight convert: WcatT[n][k] (n-major), W2T[n][k] ----------------
__global__ void wcvt_kernel(const float* __restrict__ W1, const float* __restrict__ Wskip,
                            const float* __restrict__ W2,
                            ushortT* __restrict__ WcatT, ushortT* __restrict__ W2T) {
    int id = blockIdx.x * blockDim.x + threadIdx.x;
    if (id < NCAT * IN_F) {
        int n = id >> 9;
        int k = id & 511;
        float v = (n < HID_F) ? W1[(size_t)k * HID_F + n]
                              : Wskip[(size_t)k * OUT_F + (n - HID_F)];
        WcatT[id] = f2bf(v);
    } else if (id < NCAT * IN_F + OUT_F * HID_F) {
        int j = id - NCAT * IN_F;
        int n = j >> 8;
        int k = j & 255;
        W2T[j] = f2bf(W2[(size_t)k * OUT_F + n]);
    }
}

// ---------------- GEMM1 v4: fused rownorm, x fp32 in, LDS-staged coalesced epilogue ----
// BM=64, all 320 cols, 8 waves (2x4), wave tile 32x80
#define G1_BM 64
#define G1_BK 64
#define PITCH 72              // bf16 elems per LDS row (144 B)
#define H1S_PITCH 264         // epilogue h1 stage pitch (bf16)
#define SKS_PITCH 68          // epilogue skip stage pitch (f32)
__global__ __launch_bounds__(512) void gemm1_v4_kernel(const float* __restrict__ x,
                                                       const ushortT* __restrict__ WcatT,
                                                       ushortT* __restrict__ h1b,
                                                       float* __restrict__ skip) {
    __shared__ char smem[55296];
    __shared__ float rn_s[G1_BM];
    ushortT* As = (ushortT*)smem;                 // 64*72 bf16 = 9216 B
    ushortT* Bs = As + G1_BM * PITCH;             // 320*72 bf16 = 46080 B
    ushortT* h1_s = (ushortT*)smem;               // 64*264 bf16 = 33792 B
    float* skip_s = (float*)(smem + 33792);       // 64*68 f32 = 17408 B

    const int t = threadIdx.x;
    const int lane = t & 63;
    const int wid = t >> 6;                // 8 waves
    const int wr = wid >> 2, wc = wid & 3; // wave tile 32x80
    const int lr = lane & 15, lk = lane >> 4;
    const int brow = blockIdx.x * G1_BM;
    const int sr = t >> 3, sl = t & 7;     // staging: row (0..63), 8-elem slot (0..7)

    int arow = brow + sr;
    arow = (arow < N_NODES) ? arow : (N_NODES - 1);
    const float* xrow = x + (size_t)arow * IN_F + sl * 8;

    f32x4 acc[2][5] = {};
    float4 af0, af1;
    uint4 breg[5];
    float ss = 0.0f;

    af0 = *(const float4*)xrow;
    af1 = *(const float4*)(xrow + 4);
    #pragma unroll
    for (int i = 0; i < 5; ++i)
        breg[i] = *(const uint4*)(WcatT + (size_t)(sr + 64 * i) * IN_F + sl * 8);

    for (int k0 = 0; k0 < IN_F; k0 += G1_BK) {
        // clean + sumsq + convert this k-slice
        float c[8];
        c[0] = clean0(af0.x); c[1] = clean0(af0.y); c[2] = clean0(af0.z); c[3] = clean0(af0.w);
        c[4] = clean0(af1.x); c[5] = clean0(af1.y); c[6] = clean0(af1.z); c[7] = clean0(af1.w);
        #pragma unroll
        for (int i = 0; i < 8; ++i) ss = fmaf(c[i], c[i], ss);
        uint4 au;
        au.x = (unsigned)f2bf(c[0]) | ((unsigned)f2bf(c[1]) << 16);
        au.y = (unsigned)f2bf(c[2]) | ((unsigned)f2bf(c[3]) << 16);
        au.z = (unsigned)f2bf(c[4]) | ((unsigned)f2bf(c[5]) << 16);
        au.w = (unsigned)f2bf(c[6]) | ((unsigned)f2bf(c[7]) << 16);

        __syncthreads();
        *(uint4*)&As[sr * PITCH + sl * 8] = au;
        #pragma unroll
        for (int i = 0; i < 5; ++i)
            *(uint4*)&Bs[(sr + 64 * i) * PITCH + sl * 8] = breg[i];
        __syncthreads();

        if (k0 + G1_BK < IN_F) {
            int kn = k0 + G1_BK;
            af0 = *(const float4*)(xrow + kn);
            af1 = *(const float4*)(xrow + kn + 4);
            #pragma unroll
            for (int i = 0; i < 5; ++i)
                breg[i] = *(const uint4*)(WcatT + (size_t)(sr + 64 * i) * IN_F + kn + sl * 8);
        }
        #pragma unroll
        for (int kk = 0; kk < 2; ++kk) {
            short8 a[2], b[5];
            #pragma unroll
            for (int m = 0; m < 2; ++m)
                a[m] = *(const short8*)&As[(wr * 32 + m * 16 + lr) * PITCH + kk * 32 + lk * 8];
            #pragma unroll
            for (int n = 0; n < 5; ++n)
                b[n] = *(const short8*)&Bs[(wc * 80 + n * 16 + lr) * PITCH + kk * 32 + lk * 8];
            #pragma unroll
            for (int m = 0; m < 2; ++m)
                #pragma unroll
                for (int n = 0; n < 5; ++n)
                    acc[m][n] = __builtin_amdgcn_mfma_f32_16x16x32_bf16(a[m], b[n], acc[m][n], 0, 0, 0);
        }
    }

    // row norm: reduce sumsq over the 8 staging lanes of each row
    ss += __shfl_xor(ss, 1);
    ss += __shfl_xor(ss, 2);
    ss += __shfl_xor(ss, 4);
    if (sl == 0) rn_s[sr] = 1.0f / fmaxf(sqrtf(ss), L2_EPS);
    __syncthreads();   // rn_s visible; all MFMA LDS reads done -> safe to overwrite As/Bs

    // stage epilogue tile into LDS (scaled by row norm)
    #pragma unroll
    for (int m = 0; m < 2; ++m) {
        int row0 = wr * 32 + m * 16 + lk * 4;
        #pragma unroll
        for (int n = 0; n < 5; ++n) {
            int col = wc * 80 + n * 16 + lr;
            if (col < HID_F) {
                #pragma unroll
                for (int v = 0; v < 4; ++v)
                    h1_s[(row0 + v) * H1S_PITCH + col] = f2bf(acc[m][n][v] * rn_s[row0 + v]);
            } else {
                int c2 = col - HID_F;
                #pragma unroll
                for (int v = 0; v < 4; ++v)
                    skip_s[(row0 + v) * SKS_PITCH + c2] = acc[m][n][v] * rn_s[row0 + v];
            }
        }
    }
    __syncthreads();

    // coalesced global stores: h1b 64 rows x 512B, skip 64 rows x 256B
    #pragma unroll
    for (int it = 0; it < 4; ++it) {
        int id = it * 512 + t;
        int row = id >> 5, s8 = id & 31;
        int grow = brow + row;
        if (grow < N_NODES)
            *(uint4*)(h1b + (size_t)grow * HID_F + s8 * 8) =
                *(const uint4*)&h1_s[row * H1S_PITCH + s8 * 8];
    }
    #pragma unroll
    for (int it = 0; it < 2; ++it) {
        int id = it * 512 + t;
        int row = id >> 4, s4 = id & 15;
        int grow = brow + row;
        if (grow < N_NODES)
            *(uint4*)(skip + (size_t)grow * OUT_F + s4 * 4) =
                *(const uint4*)&skip_s[row * SKS_PITCH + s4 * 4];
    }
}

// ---------------- fused agg1 + bias + LayerNorm + ReLU, half-wave per node ----------------
__global__ __launch_bounds__(256) void agg1_ln_kernel(const ushortT* __restrict__ h1b,
                                                      const float* __restrict__ dinv,
                                                      const int* __restrict__ rowptr,
                                                      const int* __restrict__ csr_src,
                                                      const float* __restrict__ csr_w,
                                                      const float* __restrict__ b1,
                                                      const float* __restrict__ gamma,
                                                      const float* __restrict__ beta,
                                                      ushortT* __restrict__ lnb) {
    int node = blockIdx.x * 8 + (threadIdx.x >> 5);
    if (node >= N_NODES) return;
    int l = threadIdx.x & 31;
    const uint4* hp = (const uint4*)h1b;       // 32 uint4 per row

    float di = dinv[node];
    float ws = di * di;
    float a[8], g[8];
    bf8_to_f32(hp[(size_t)node * 32 + l], a);
    #pragma unroll
    for (int i = 0; i < 8; ++i) a[i] *= ws;

    int jb = rowptr[node], je = rowptr[node + 1];
    int j = jb;
    for (; j + 3 < je; j += 4) {
        int s0 = csr_src[j];
        int s1 = csr_src[j + 1];
        int s2 = csr_src[j + 2];
        int s3 = csr_src[j + 3];
        float w0 = csr_w[j], w1 = csr_w[j + 1], w2 = csr_w[j + 2], w3 = csr_w[j + 3];
        uint4 u0 = hp[(size_t)s0 * 32 + l];
        uint4 u1 = hp[(size_t)s1 * 32 + l];
        uint4 u2 = hp[(size_t)s2 * 32 + l];
        uint4 u3 = hp[(size_t)s3 * 32 + l];
        bf8_to_f32(u0, g);
        #pragma unroll
        for (int i = 0; i < 8; ++i) a[i] = fmaf(g[i], w0, a[i]);
        bf8_to_f32(u1, g);
        #pragma unroll
        for (int i = 0; i < 8; ++i) a[i] = fmaf(g[i], w1, a[i]);
        bf8_to_f32(u2, g);
        #pragma unroll
        for (int i = 0; i < 8; ++i) a[i] = fmaf(g[i], w2, a[i]);
        bf8_to_f32(u3, g);
        #pragma unroll
        for (int i = 0; i < 8; ++i) a[i] = fmaf(g[i], w3, a[i]);
    }
    for (; j < je; ++j) {
        int s0 = csr_src[j];
        float w0 = csr_w[j];
        bf8_to_f32(hp[(size_t)s0 * 32 + l], g);
        #pragma unroll
        for (int i = 0; i < 8; ++i) a[i] = fmaf(g[i], w0, a[i]);
    }

    float4 ba = *(const float4*)(b1 + l * 8);
    float4 bb = *(const float4*)(b1 + l * 8 + 4);
    a[0] += ba.x; a[1] += ba.y; a[2] += ba.z; a[3] += ba.w;
    a[4] += bb.x; a[5] += bb.y; a[6] += bb.z; a[7] += bb.w;

    float s = 0.0f, s2 = 0.0f;
    #pragma unroll
    for (int i = 0; i < 8; ++i) { s += a[i]; s2 = fmaf(a[i], a[i], s2); }
    #pragma unroll
    for (int off = 16; off > 0; off >>= 1) {
        s += __shfl_xor(s, off);
        s2 += __shfl_xor(s2, off);
    }
    float mu = s * (1.0f / HID_F);
    float var = s2 * (1.0f / HID_F) - mu * mu;
    float rs = rsqrtf(var + LN_EPS);

    float4 ga = *(const float4*)(gamma + l * 8);
    float4 gb = *(const float4*)(gamma + l * 8 + 4);
    float4 ea = *(const float4*)(beta + l * 8);
    float4 eb = *(const float4*)(beta + l * 8 + 4);
    float gm[8] = {ga.x, ga.y, ga.z, ga.w, gb.x, gb.y, gb.z, gb.w};
    float be[8] = {ea.x, ea.y, ea.z, ea.w, eb.x, eb.y, eb.z, eb.w};
    ushortT o[8];
    #pragma unroll
    for (int i = 0; i < 8; ++i)
        o[i] = f2bf(fmaxf(0.0f, (a[i] - mu) * rs * gm[i] + be[i]));
    *(uint4*)(lnb + (size_t)node * HID_F + l * 8) = *(uint4*)o;
}

// ---------------- GEMM2 v4: BM=64, 4 waves (2x2), LDS-staged coalesced epilogue ----------------
__global__ __launch_bounds__(256) void gemm2_v4_kernel(const ushortT* __restrict__ lnb,
                                                       const ushortT* __restrict__ W2T,
                                                       float* __restrict__ h2) {
    __shared__ char smem2[18432];
    ushortT* As = (ushortT*)smem2;             // 64*72
    ushortT* Bs = As + G1_BM * PITCH;          // 64*72
    float* h2_s = (float*)smem2;               // 64*68 f32 = 17408 B

    const int t = threadIdx.x;
    const int lane = t & 63;
    const int wid = t >> 6;                // 4 waves
    const int wr = wid >> 1, wc = wid & 1; // wave tile 32x32
    const int lr = lane & 15, lk = lane >> 4;
    const int brow = blockIdx.x * G1_BM;
    const int sr = t >> 3, sl = t & 7;     // staging row (0..31), slot

    f32x4 acc[2][2] = {};
    uint4 areg[2], breg[2];

    #pragma unroll
    for (int i = 0; i < 2; ++i) {
        int r = brow + sr + 32 * i;
        r = (r < N_NODES) ? r : (N_NODES - 1);
        areg[i] = *(const uint4*)(lnb + (size_t)r * HID_F + sl * 8);
        breg[i] = *(const uint4*)(W2T + (size_t)(sr + 32 * i) * HID_F + sl * 8);
    }

    for (int k0 = 0; k0 < HID_F; k0 += G1_BK) {
        __syncthreads();
        #pragma unroll
        for (int i = 0; i < 2; ++i) {
            *(uint4*)&As[(sr + 32 * i) * PITCH + sl * 8] = areg[i];
            *(uint4*)&Bs[(sr + 32 * i) * PITCH + sl * 8] = breg[i];
        }
        __syncthreads();
        if (k0 + G1_BK < HID_F) {
            int kn = k0 + G1_BK;
            #pragma unroll
            for (int i = 0; i < 2; ++i) {
                int r = brow + sr + 32 * i;
                r = (r < N_NODES) ? r : (N_NODES - 1);
                areg[i] = *(const uint4*)(lnb + (size_t)r * HID_F + kn + sl * 8);
                breg[i] = *(const uint4*)(W2T + (size_t)(sr + 32 * i) * HID_F + kn + sl * 8);
            }
        }
        #pragma unroll
        for (int kk = 0; kk < 2; ++kk) {
            short8 a[2], b[2];
            #pragma unroll
            for (int m = 0; m < 2; ++m)
                a[m] = *(const short8*)&As[(wr * 32 + m * 16 + lr) * PITCH + kk * 32 + lk * 8];
            #pragma unroll
            for (int n = 0; n < 2; ++n)
                b[n] = *(const short8*)&Bs[(wc * 32 + n * 16 + lr) * PITCH + kk * 32 + lk * 8];
            #pragma unroll
            for (int m = 0; m < 2; ++m)
                #pragma unroll
                for (int n = 0; n < 2; ++n)
                    acc[m][n] = __builtin_amdgcn_mfma_f32_16x16x32_bf16(a[m], b[n], acc[m][n], 0, 0, 0);
        }
    }

    __syncthreads();
    #pragma unroll
    for (int m = 0; m < 2; ++m) {
        int row0 = wr * 32 + m * 16 + lk * 4;
        #pragma unroll
        for (int n = 0; n < 2; ++n) {
            int col = wc * 32 + n * 16 + lr;
            #pragma unroll
            for (int v = 0; v < 4; ++v)
                h2_s[(row0 + v) * SKS_PITCH + col] = acc[m][n][v];
        }
    }
    __syncthreads();
    #pragma unroll
    for (int it = 0; it < 4; ++it) {
        int id = it * 256 + t;
        int row = id >> 4, s4 = id & 15;
        int grow = brow + row;
        if (grow < N_NODES)
            *(uint4*)(h2 + (size_t)grow * OUT_F + s4 * 4) =
                *(const uint4*)&h2_s[row * SKS_PITCH + s4 * 4];
    }
}

// ---------------- aggregation 2: quarter-wave per node, float4 lanes ----------------
__global__ __launch_bounds__(256) void agg2_gather_kernel(const float* __restrict__ h2,
                                                          const float* __restrict__ skip,
                                                          const float* __restrict__ b2,
                                                          const float* __restrict__ dinv,
                                                          const int* __restrict__ rowptr,
                                                          const int* __restrict__ csr_src,
                                                          const float* __restrict__ csr_w,
                                                          float* __restrict__ out) {
    int node = blockIdx.x * 16 + (threadIdx.x >> 4);
    if (node >= N_NODES) return;
    int l = threadIdx.x & 15;
    const float4* hp = (const float4*)h2;      // 16 float4 per row

    float di = dinv[node];
    float ws = di * di;
    float4 sv = hp[(size_t)node * 16 + l];
    float ax = sv.x * ws, ay = sv.y * ws, az = sv.z * ws, aw = sv.w * ws;

    int jb = rowptr[node], je = rowptr[node + 1];
    int j = jb;
    for (; j + 3 < je; j += 4) {
        int s0 = csr_src[j];
        int s1 = csr_src[j + 1];
        int s2 = csr_src[j + 2];
        int s3 = csr_src[j + 3];
        float w0 = csr_w[j], w1 = csr_w[j + 1], w2 = csr_w[j + 2], w3 = csr_w[j + 3];
        float4 v0 = hp[(size_t)s0 * 16 + l];
        float4 v1 = hp[(size_t)s1 * 16 + l];
        float4 v2 = hp[(size_t)s2 * 16 + l];
        float4 v3 = hp[(size_t)s3 * 16 + l];
        ax = fmaf(v0.x, w0, ax); ay = fmaf(v0.y, w0, ay); az = fmaf(v0.z, w0, az); aw = fmaf(v0.w, w0, aw);
        ax = fmaf(v1.x, w1, ax); ay = fmaf(v1.y, w1, ay); az = fmaf(v1.z, w1, az); aw = fmaf(v1.w, w1, aw);
        ax = fmaf(v2.x, w2, ax); ay = fmaf(v2.y, w2, ay); az = fmaf(v2.z, w2, az); aw = fmaf(v2.w, w2, aw);
        ax = fmaf(v3.x, w3, ax); ay = fmaf(v3.y, w3, ay); az = fmaf(v3.z, w3, az); aw = fmaf(v3.w, w3, aw);
    }
    for (; j < je; ++j) {
        int s0 = csr_src[j];
        float w0 = csr_w[j];
        float4 v0 = hp[(size_t)s0 * 16 + l];
        ax = fmaf(v0.x, w0, ax); ay = fmaf(v0.y, w0, ay); az = fmaf(v0.z, w0, az); aw = fmaf(v0.w, w0, aw);
    }

    float4 sk = ((const float4*)skip)[(size_t)node * 16 + l];
    float4 bb = ((const float4*)b2)[l];
    float r[4] = {ax + sk.x + bb.x, ay + sk.y + bb.y, az + sk.z + bb.z, aw + sk.w + bb.w};
    #pragma unroll
    for (int i = 0; i < 4; ++i) {
        float v = r[i];
        if (isnan(v)) v = 0.0f;
        else if (isinf(v)) v = (v > 0.0f) ? 20.0f : -20.0f;
        r[i] = v;
    }
    ((float4*)out)[(size_t)node * 16 + l] = make_float4(r[0], r[1], r[2], r[3]);
}

extern "C" void kernel_launch(void* const* d_in, const int* in_sizes, int n_in,
                              void* d_out, int out_size, void* d_ws, size_t ws_size,
                              hipStream_t stream) {
    const float* x     = (const float*)d_in[0];
    const int*   ei    = (const int*)d_in[1];
    const float* W1    = (const float*)d_in[2];
    const float* b1    = (const float*)d_in[3];
    const float* gamma = (const float*)d_in[4];
    const float* beta  = (const float*)d_in[5];
    const float* W2    = (const float*)d_in[6];
    const float* b2    = (const float*)d_in[7];
    const float* Wskip = (const float*)d_in[8];
    float* out = (float*)d_out;

    const int* src = ei;
    const int* dst = ei + E_EDGES;

    // ws layout
    ushortT* h1b   = (ushortT*)d_ws;                       // N*256 bf16
    ushortT* lnb   = h1b + (size_t)N_NODES * HID_F;        // N*256 bf16
    float* h2      = (float*)(lnb + (size_t)N_NODES * HID_F);  // N*64 f32
    float* skip    = h2 + (size_t)N_NODES * OUT_F;         // N*64 f32
    float* dinv    = skip + (size_t)N_NODES * OUT_F;       // N
    float* csr_w   = dinv + N_NODES;                       // E
    ushortT* WcatT = (ushortT*)(csr_w + E_EDGES);          // 320*512
    ushortT* W2T   = WcatT + (size_t)NCAT * IN_F;          // 64*256
    int* deg       = (int*)(W2T + (size_t)OUT_F * HID_F);  // N
    int* rowptr    = deg + N_NODES;                        // N+1
    int* cursor    = rowptr + N_NODES + 1;                 // N
    int* csr_src   = cursor + N_NODES;                     // E

    // ---- CSR build + dinv ----
    zero_deg_kernel<<<(N_NODES + 255) / 256, 256, 0, stream>>>(deg);
    count_deg_kernel<<<(E_EDGES + 255) / 256, 256, 0, stream>>>(dst, deg);
    dinv_kernel<<<(N_NODES + 255) / 256, 256, 0, stream>>>(deg, dinv);
    scan_kernel<<<1, SCAN_T, 0, stream>>>(deg, rowptr, cursor);
    scatter_kernel<<<(E_EDGES + 255) / 256, 256, 0, stream>>>(src, dst, dinv, cursor,
                                                              csr_src, csr_w);

    // ---- weight convert ----
    wcvt_kernel<<<(NCAT * IN_F + OUT_F * HID_F + 255) / 256, 256, 0, stream>>>(
        W1, Wskip, W2, WcatT, W2T);

    // ---- GEMM1 v4 (fused rownorm; h1b bf16 + skip f32) ----
    gemm1_v4_kernel<<<(N_NODES + G1_BM - 1) / G1_BM, 512, 0, stream>>>(x, WcatT, h1b, skip);

    // ---- fused agg1 + bias + LN + ReLU -> lnb ----
    agg1_ln_kernel<<<(N_NODES + 7) / 8, 256, 0, stream>>>(h1b, dinv, rowptr, csr_src,
                                                          csr_w, b1, gamma, beta, lnb);

    // ---- GEMM2 v4 ----
    gemm2_v4_kernel<<<(N_NODES + G1_BM - 1) / G1_BM, 256, 0, stream>>>(lnb, W2T, h2);

    // ---- aggregation 2 (quarter-wave gather, fused epilogue) ----
    agg2_gather_kernel<<<(N_NODES + 15) / 16, 256, 0, stream>>>(h2, skip, b2, dinv, rowptr,
                                                                csr_src, csr_w, out);
}